// Round 3
// baseline (686.772 us; speedup 1.0000x reference)
//
#include <hip/hip_runtime.h>
#include <math.h>

typedef short bf16x8 __attribute__((ext_vector_type(8)));
typedef float f32x4 __attribute__((ext_vector_type(4)));

#define NB 16
#define CC 1024
#define HW 1024
#define CQK 128
#define EPS 1e-5f

// ---- ws byte offsets (total ~166 MiB) ----
#define OFF_A     0
#define OFF_STATS 65536
#define OFF_CM    66048
#define OFF_WHI   131584
#define OFF_WLO   (OFF_WHI + 2621440)
#define OFF_QF    (OFF_WLO + 2621440)
#define OFF_KF    (OFF_QF + 8388608)
#define OFF_QTH   (OFF_KF + 8388608)
#define OFF_QTL   (OFF_QTH + 4194304)
#define OFF_KTH   (OFF_QTL + 4194304)
#define OFF_KTL   (OFF_KTH + 4194304)
#define OFF_VH    (OFF_KTL + 4194304)
#define OFF_VL    (OFF_VH + 33554432)
#define OFF_XTH   (OFF_VL + 33554432)
#define OFF_XTL   (OFF_XTH + 33554432)
#define OFF_ATTN  OFF_XTH                    /* overlay: attn/P lives where xT was */
#define OFF_PMAX  (OFF_XTL + 33554432)

__device__ __forceinline__ ushort bf16_rn(float f) {
    union { float f; unsigned u; } v; v.f = f;
    unsigned u = v.u;
    return (ushort)((u + 0x7FFFu + ((u >> 16) & 1u)) >> 16);
}
__device__ __forceinline__ float bf16f(ushort h) {
    union { unsigned u; float f; } v; v.u = ((unsigned)h) << 16;
    return v.f;
}
__device__ __forceinline__ void split2(float f, ushort& h, ushort& l) {
    h = bf16_rn(f);
    l = bf16_rn(f - bf16f(h));
}

// ================= small kernels (unchanged structure) =================
__global__ void conv_head(const float* __restrict__ x, const float* __restrict__ hwt,
                          float* __restrict__ a) {
    int n = blockIdx.x >> 5;
    int h = blockIdx.x & 31;
    int w = threadIdx.x & 31;
    int cg = threadIdx.x >> 5;
    float acc = 0.f;
    for (int c = cg; c < CC; c += 8) {
        const float* xp = x + ((size_t)(n * CC + c) << 10);
        const float* wp = hwt + c * 9;
        #pragma unroll
        for (int dy = -1; dy <= 1; ++dy) {
            int hh = h + dy;
            if (hh < 0 || hh > 31) continue;
            #pragma unroll
            for (int dx = -1; dx <= 1; ++dx) {
                int ww = w + dx;
                if (ww < 0 || ww > 31) continue;
                acc += xp[(hh << 5) + ww] * wp[(dy + 1) * 3 + (dx + 1)];
            }
        }
    }
    __shared__ float red[8][33];
    red[cg][w] = acc;
    __syncthreads();
    if (cg == 0) {
        float s = 0.f;
        #pragma unroll
        for (int g = 0; g < 8; ++g) s += red[g][w];
        a[(n << 10) + (h << 5) + w] = s;
    }
}

__global__ void bn_stats(const float* __restrict__ a, float* __restrict__ stats) {
    int t = threadIdx.x;
    float s = 0.f, ss = 0.f;
    for (int i = t; i < NB * HW; i += 256) { float v = a[i]; s += v; ss += v * v; }
    __shared__ float rs[256], rss[256];
    rs[t] = s; rss[t] = ss;
    __syncthreads();
    for (int off = 128; off > 0; off >>= 1) {
        if (t < off) { rs[t] += rs[t + off]; rss[t] += rss[t + off]; }
        __syncthreads();
    }
    if (t == 0) {
        float mu = rs[0] / (NB * HW);
        float var = rss[0] / (NB * HW) - mu * mu;
        stats[0] = mu;
        stats[1] = rsqrtf(var + EPS);
    }
}

__global__ void ccam_kernel(const float* __restrict__ a, const float* __restrict__ stats,
                            const float* __restrict__ bn_w, const float* __restrict__ bn_b,
                            float* __restrict__ cm, float* __restrict__ out_ccam) {
    int i = blockIdx.x * 256 + threadIdx.x;
    float z = (a[i] - stats[0]) * stats[1] * bn_w[0] + bn_b[0];
    float sg = 1.f / (1.f + expf(-z));
    cm[i] = sg;
    out_ccam[i] = sg;
}

__global__ void fgbg_kernel(const float* __restrict__ x, const float* __restrict__ cm,
                            float* __restrict__ out_fg, float* __restrict__ out_bg) {
    int gid = blockIdx.x * blockDim.x + threadIdx.x;
    int wid = gid >> 6;
    int lane = threadIdx.x & 63;
    int n = wid >> 10, c = wid & 1023;
    const float* xp = x + ((size_t)(n * CC + c) << 10);
    const float* cp = cm + (n << 10);
    float sf = 0.f, sa = 0.f;
    for (int h = lane; h < HW; h += 64) { float xv = xp[h]; sf += cp[h] * xv; sa += xv; }
    for (int off = 32; off > 0; off >>= 1) { sf += __shfl_xor(sf, off); sa += __shfl_xor(sa, off); }
    if (lane == 0) {
        float fgv = sf * (1.f / HW);
        out_fg[(n << 10) + c] = fgv;
        out_bg[(n << 10) + c] = sa * (1.f / HW) - fgv;
    }
}

// ================= split / transpose pre-passes =================
// W rows: [0,128)=q_w, [128,256)=k_w, [256,1280)=v_w
__global__ void split_w(const float* __restrict__ qw, const float* __restrict__ kw,
                        const float* __restrict__ vw,
                        ushort* __restrict__ wh, ushort* __restrict__ wl) {
    size_t e = ((size_t)blockIdx.x * 256 + threadIdx.x) * 4;
    float4 v;
    if (e < 131072)       v = *(const float4*)(qw + e);
    else if (e < 262144)  v = *(const float4*)(kw + e - 131072);
    else                  v = *(const float4*)(vw + e - 262144);
    ushort4 h4, l4;
    split2(v.x, h4.x, l4.x); split2(v.y, h4.y, l4.y);
    split2(v.z, h4.z, l4.z); split2(v.w, h4.w, l4.w);
    *(ushort4*)&wh[e] = h4;
    *(ushort4*)&wl[e] = l4;
}

// x [n][c][hw] -> xT [n][hw][c] (hi/lo bf16)
__global__ void splitT_x(const float* __restrict__ x,
                         ushort* __restrict__ xh, ushort* __restrict__ xl) {
    int n = blockIdx.z, cb = blockIdx.y, hb = blockIdx.x;
    __shared__ float tile[32][33];
    int t = threadIdx.x;
    int r = t >> 3, c4 = (t & 7) << 2;
    const float* s = x + ((size_t)(n * CC + cb * 32 + r) << 10) + hb * 32 + c4;
    float4 v = *(const float4*)s;
    tile[r][c4] = v.x; tile[r][c4 + 1] = v.y; tile[r][c4 + 2] = v.z; tile[r][c4 + 3] = v.w;
    __syncthreads();
    int hw_l = t >> 3, cg = (t & 7) << 2;
    float f0 = tile[cg + 0][hw_l], f1 = tile[cg + 1][hw_l];
    float f2 = tile[cg + 2][hw_l], f3 = tile[cg + 3][hw_l];
    ushort4 h4, l4;
    split2(f0, h4.x, l4.x); split2(f1, h4.y, l4.y);
    split2(f2, h4.z, l4.z); split2(f3, h4.w, l4.w);
    size_t di = ((size_t)(n * HW + hb * 32 + hw_l) << 10) + cb * 32 + cg;
    *(ushort4*)&xh[di] = h4;
    *(ushort4*)&xl[di] = l4;
}

// q,k fp32 [n][128 o][1024 hw] -> qT/kT [n][1024 hw][128 o] (hi/lo bf16)
__global__ void splitT_qk(const float* __restrict__ qf, const float* __restrict__ kf,
                          ushort* __restrict__ qth, ushort* __restrict__ qtl,
                          ushort* __restrict__ kth, ushort* __restrict__ ktl) {
    int z = blockIdx.z;
    int n = z >> 1, which = z & 1;
    const float* src = which ? kf : qf;
    ushort* dh = which ? kth : qth;
    ushort* dl = which ? ktl : qtl;
    int ob = blockIdx.y, hb = blockIdx.x;
    __shared__ float tile[32][33];
    int t = threadIdx.x;
    int r = t >> 3, c4 = (t & 7) << 2;
    const float* s = src + ((size_t)(n * CQK + ob * 32 + r) << 10) + hb * 32 + c4;
    float4 v = *(const float4*)s;
    tile[r][c4] = v.x; tile[r][c4 + 1] = v.y; tile[r][c4 + 2] = v.z; tile[r][c4 + 3] = v.w;
    __syncthreads();
    int hw_l = t >> 3, og = (t & 7) << 2;
    float f0 = tile[og + 0][hw_l], f1 = tile[og + 1][hw_l];
    float f2 = tile[og + 2][hw_l], f3 = tile[og + 3][hw_l];
    ushort4 h4, l4;
    split2(f0, h4.x, l4.x); split2(f1, h4.y, l4.y);
    split2(f2, h4.z, l4.z); split2(f3, h4.w, l4.w);
    size_t di = ((size_t)(n * HW + hb * 32 + hw_l) << 7) + ob * 32 + og;
    *(ushort4*)&dh[di] = h4;
    *(ushort4*)&dl[di] = l4;
}

// ================= split-bf16 MFMA GEMM core =================
// Block 128x128, 4 waves (2x2), wave tile 64x64 = 4x4 frags of 16x16, K-step 32.
// A,B operands stored [row][k] contiguous; LDS tiles [128][40] (pad kills conflicts).
__device__ __forceinline__ void split_gemm_loop(
        const ushort* __restrict__ Ah_g, const ushort* __restrict__ Al_g, int ap,
        const ushort* __restrict__ Bh_g, const ushort* __restrict__ Bl_g, int bp,
        int K, ushort* lds, f32x4 acc[4][4]) {
    const int t = threadIdx.x;
    const int lane = t & 63, wid = t >> 6;
    const int lr = lane & 15, kg = lane >> 4;
    const int wm = (wid >> 1) << 6, wn = (wid & 1) << 6;
    ushort* Ah = lds;
    ushort* Al = lds + 5120;
    ushort* Bh = lds + 10240;
    ushort* Bl = lds + 15360;
    const int r_ = t >> 1, ch_ = (t & 1) << 4;
    const int lo = r_ * 40 + ch_;
    for (int k0 = 0; k0 < K; k0 += 32) {
        __syncthreads();
        {
            const ushort* g0 = Ah_g + (size_t)r_ * ap + k0 + ch_;
            const ushort* g1 = Al_g + (size_t)r_ * ap + k0 + ch_;
            const ushort* g2 = Bh_g + (size_t)r_ * bp + k0 + ch_;
            const ushort* g3 = Bl_g + (size_t)r_ * bp + k0 + ch_;
            *(uint4*)&Ah[lo]     = *(const uint4*)g0;
            *(uint4*)&Ah[lo + 8] = *(const uint4*)(g0 + 8);
            *(uint4*)&Al[lo]     = *(const uint4*)g1;
            *(uint4*)&Al[lo + 8] = *(const uint4*)(g1 + 8);
            *(uint4*)&Bh[lo]     = *(const uint4*)g2;
            *(uint4*)&Bh[lo + 8] = *(const uint4*)(g2 + 8);
            *(uint4*)&Bl[lo]     = *(const uint4*)g3;
            *(uint4*)&Bl[lo + 8] = *(const uint4*)(g3 + 8);
        }
        __syncthreads();
        bf16x8 ah[4], al[4], bh[4], bl[4];
        #pragma unroll
        for (int i = 0; i < 4; ++i) {
            ah[i] = *(const bf16x8*)&Ah[(wm + i * 16 + lr) * 40 + kg * 8];
            al[i] = *(const bf16x8*)&Al[(wm + i * 16 + lr) * 40 + kg * 8];
            bh[i] = *(const bf16x8*)&Bh[(wn + i * 16 + lr) * 40 + kg * 8];
            bl[i] = *(const bf16x8*)&Bl[(wn + i * 16 + lr) * 40 + kg * 8];
        }
        #pragma unroll
        for (int i = 0; i < 4; ++i)
            #pragma unroll
            for (int j = 0; j < 4; ++j) {
                acc[i][j] = __builtin_amdgcn_mfma_f32_16x16x32_bf16(ah[i], bh[j], acc[i][j], 0, 0, 0);
                acc[i][j] = __builtin_amdgcn_mfma_f32_16x16x32_bf16(ah[i], bl[j], acc[i][j], 0, 0, 0);
                acc[i][j] = __builtin_amdgcn_mfma_f32_16x16x32_bf16(al[i], bh[j], acc[i][j], 0, 0, 0);
            }
    }
}

// K4: QKV. A = W[1280][1024] (hi/lo), B = xT[n][hw][c] (hi/lo). D[m][j].
__global__ __launch_bounds__(256) void qkv_gemm(
        const ushort* __restrict__ Whi, const ushort* __restrict__ Wlo,
        const ushort* __restrict__ xth, const ushort* __restrict__ xtl,
        const float* __restrict__ qb, const float* __restrict__ kb,
        const float* __restrict__ vb,
        float* __restrict__ qf, float* __restrict__ kf,
        ushort* __restrict__ vh, ushort* __restrict__ vl) {
    __shared__ ushort lds[20480];
    int n = blockIdx.z, m0 = blockIdx.y << 7, j0 = blockIdx.x << 7;
    f32x4 acc[4][4];
    #pragma unroll
    for (int i = 0; i < 4; ++i)
        #pragma unroll
        for (int j = 0; j < 4; ++j) acc[i][j] = (f32x4){0.f, 0.f, 0.f, 0.f};
    split_gemm_loop(Whi + (size_t)m0 * CC, Wlo + (size_t)m0 * CC, CC,
                    xth + ((size_t)(n * HW + j0)) * CC, xtl + ((size_t)(n * HW + j0)) * CC, CC,
                    CC, lds, acc);
    const int t = threadIdx.x, lane = t & 63, wid = t >> 6;
    const int lr = lane & 15, kg = lane >> 4;
    const int wm = (wid >> 1) << 6, wn = (wid & 1) << 6;
    if (m0 < 256) {
        float* dst = (m0 == 0) ? qf : kf;
        const float* bp = (m0 == 0) ? qb : kb;
        #pragma unroll
        for (int mi = 0; mi < 4; ++mi)
            #pragma unroll
            for (int r = 0; r < 4; ++r) {
                int m = wm + mi * 16 + kg * 4 + r;
                float bias = bp[m];
                #pragma unroll
                for (int nj = 0; nj < 4; ++nj) {
                    int j = j0 + wn + nj * 16 + lr;
                    dst[((size_t)(n * CQK + m) << 10) + j] = acc[mi][nj][r] + bias;
                }
            }
    } else {
        int mo = m0 - 256;
        #pragma unroll
        for (int mi = 0; mi < 4; ++mi)
            #pragma unroll
            for (int r = 0; r < 4; ++r) {
                int m = mo + wm + mi * 16 + kg * 4 + r;
                float bias = vb[m];
                #pragma unroll
                for (int nj = 0; nj < 4; ++nj) {
                    int j = j0 + wn + nj * 16 + lr;
                    float val = acc[mi][nj][r] + bias;
                    ushort h, l; split2(val, h, l);
                    size_t idx = ((size_t)(n * CC + m) << 10) + j;
                    vh[idx] = h; vl[idx] = l;
                }
            }
    }
}

// K5: scores. A = qT[n][i][o], B = kT[n][j][o], K=128. D[i][j] fp32 -> attn.
__global__ __launch_bounds__(256) void score_gemm(
        const ushort* __restrict__ qth, const ushort* __restrict__ qtl,
        const ushort* __restrict__ kth, const ushort* __restrict__ ktl,
        float* __restrict__ attn) {
    __shared__ ushort lds[20480];
    int n = blockIdx.z, i0 = blockIdx.y << 7, j0 = blockIdx.x << 7;
    f32x4 acc[4][4];
    #pragma unroll
    for (int i = 0; i < 4; ++i)
        #pragma unroll
        for (int j = 0; j < 4; ++j) acc[i][j] = (f32x4){0.f, 0.f, 0.f, 0.f};
    split_gemm_loop(qth + ((size_t)(n * HW + i0)) * CQK, qtl + ((size_t)(n * HW + i0)) * CQK, CQK,
                    kth + ((size_t)(n * HW + j0)) * CQK, ktl + ((size_t)(n * HW + j0)) * CQK, CQK,
                    CQK, lds, acc);
    const int t = threadIdx.x, lane = t & 63, wid = t >> 6;
    const int lr = lane & 15, kg = lane >> 4;
    const int wm = (wid >> 1) << 6, wn = (wid & 1) << 6;
    #pragma unroll
    for (int mi = 0; mi < 4; ++mi)
        #pragma unroll
        for (int r = 0; r < 4; ++r) {
            int irow = i0 + wm + mi * 16 + kg * 4 + r;
            #pragma unroll
            for (int nj = 0; nj < 4; ++nj) {
                int j = j0 + wn + nj * 16 + lr;
                attn[((size_t)(n * HW + irow) << 10) + j] = acc[mi][nj][r];
            }
        }
}

// K6: softmax over j, output P as hi/lo bf16 IN PLACE (row: [hi x1024 | lo x1024]).
__global__ void softmax_split(float* __restrict__ attn) {
    int row = blockIdx.x;
    float* p = attn + ((size_t)row << 10);
    int t = threadIdx.x;
    int wid = t >> 6, lane = t & 63;
    float vals[4];
    float m = -INFINITY;
    #pragma unroll
    for (int r = 0; r < 4; ++r) { vals[r] = p[t + (r << 8)]; m = fmaxf(m, vals[r]); }
    for (int off = 32; off > 0; off >>= 1) m = fmaxf(m, __shfl_xor(m, off));
    __shared__ float redm[4], reds[4];
    if (lane == 0) redm[wid] = m;
    __syncthreads();
    if (t == 0) {
        float mm = redm[0];
        for (int g = 1; g < 4; ++g) mm = fmaxf(mm, redm[g]);
        redm[0] = mm;
    }
    __syncthreads();
    m = redm[0];
    float s = 0.f;
    #pragma unroll
    for (int r = 0; r < 4; ++r) { vals[r] = expf(vals[r] - m); s += vals[r]; }
    for (int off = 32; off > 0; off >>= 1) s += __shfl_xor(s, off);
    if (lane == 0) reds[wid] = s;
    __syncthreads();
    if (t == 0) {
        float ss = reds[0];
        for (int g = 1; g < 4; ++g) ss += reds[g];
        reds[0] = ss;
    }
    __syncthreads();
    float inv = 1.f / reds[0];
    ushort* ph = (ushort*)p;
    #pragma unroll
    for (int r = 0; r < 4; ++r) {
        float pv = vals[r] * inv;
        ushort h, l; split2(pv, h, l);
        ph[t + (r << 8)] = h;
        ph[1024 + t + (r << 8)] = l;
    }
}

// K7: out. A = v[n][c][j] (hi/lo), B = P[n][i][j] (hi at row*2048, lo +1024).
// Epilogue: o = g*acc + x[c][i]; per-c max over i -> pmax[n][iblk][c].
__global__ __launch_bounds__(256) void out_gemm(
        const ushort* __restrict__ vh, const ushort* __restrict__ vl,
        const ushort* __restrict__ pus,
        const float* __restrict__ x, const float* __restrict__ gamma,
        float* __restrict__ pmax) {
    __shared__ ushort lds[20480];
    __shared__ float smax[4][64];
    int n = blockIdx.z, c0 = blockIdx.y << 7, i0 = blockIdx.x << 7;
    f32x4 acc[4][4];
    #pragma unroll
    for (int i = 0; i < 4; ++i)
        #pragma unroll
        for (int j = 0; j < 4; ++j) acc[i][j] = (f32x4){0.f, 0.f, 0.f, 0.f};
    const ushort* pb = pus + ((size_t)(n * HW + i0)) * 2048;
    split_gemm_loop(vh + ((size_t)(n * CC + c0) << 10), vl + ((size_t)(n * CC + c0) << 10), HW,
                    pb, pb + 1024, 2048,
                    HW, lds, acc);
    const int t = threadIdx.x, lane = t & 63, wid = t >> 6;
    const int lr = lane & 15, kg = lane >> 4;
    const int wm = (wid >> 1) << 6, wn = (wid & 1) << 6;
    float g = gamma[0];
    #pragma unroll
    for (int mi = 0; mi < 4; ++mi)
        #pragma unroll
        for (int r = 0; r < 4; ++r) {
            int c = c0 + wm + mi * 16 + kg * 4 + r;
            const float* xp = x + ((size_t)(n * CC + c) << 10);
            float mx = -INFINITY;
            #pragma unroll
            for (int nj = 0; nj < 4; ++nj) {
                int i = i0 + wn + nj * 16 + lr;
                mx = fmaxf(mx, g * acc[mi][nj][r] + xp[i]);
            }
            #pragma unroll
            for (int off = 1; off < 16; off <<= 1) mx = fmaxf(mx, __shfl_xor(mx, off));
            if (lr == 0) smax[wid][mi * 16 + kg * 4 + r] = mx;
        }
    __syncthreads();
    if (t < 128) {
        int half = t >> 6, cl = t & 63;
        float m = fmaxf(smax[half * 2][cl], smax[half * 2 + 1][cl]);
        pmax[((size_t)(n * 8 + blockIdx.x) << 10) + c0 + half * 64 + cl] = m;
    }
}

__global__ void gf_reduce(const float* __restrict__ pmax, float* __restrict__ gf) {
    int idx = blockIdx.x * 256 + threadIdx.x;
    int n = idx >> 10, c = idx & 1023;
    float m = -INFINITY;
    #pragma unroll
    for (int ib = 0; ib < 8; ++ib)
        m = fmaxf(m, pmax[(((size_t)(n << 3) + ib) << 10) + c]);
    gf[idx] = m;
}

extern "C" void kernel_launch(void* const* d_in, const int* in_sizes, int n_in,
                              void* d_out, int out_size, void* d_ws, size_t ws_size,
                              hipStream_t stream) {
    const float* x      = (const float*)d_in[0];
    const float* head_w = (const float*)d_in[1];
    const float* bn_w   = (const float*)d_in[2];
    const float* bn_b   = (const float*)d_in[3];
    const float* q_w    = (const float*)d_in[4];
    const float* q_b    = (const float*)d_in[5];
    const float* k_w    = (const float*)d_in[6];
    const float* k_b    = (const float*)d_in[7];
    const float* v_w    = (const float*)d_in[8];
    const float* v_b    = (const float*)d_in[9];
    const float* gamma  = (const float*)d_in[10];

    float* out      = (float*)d_out;
    float* out_fg   = out;
    float* out_bg   = out + 16384;
    float* out_ccam = out + 32768;
    float* out_gf   = out + 49152;

    char* B = (char*)d_ws;
    float*  a     = (float*)(B + OFF_A);
    float*  stats = (float*)(B + OFF_STATS);
    float*  cm    = (float*)(B + OFF_CM);
    ushort* Whi   = (ushort*)(B + OFF_WHI);
    ushort* Wlo   = (ushort*)(B + OFF_WLO);
    float*  qf    = (float*)(B + OFF_QF);
    float*  kf    = (float*)(B + OFF_KF);
    ushort* qth   = (ushort*)(B + OFF_QTH);
    ushort* qtl   = (ushort*)(B + OFF_QTL);
    ushort* kth   = (ushort*)(B + OFF_KTH);
    ushort* ktl   = (ushort*)(B + OFF_KTL);
    ushort* vh    = (ushort*)(B + OFF_VH);
    ushort* vl    = (ushort*)(B + OFF_VL);
    ushort* xth   = (ushort*)(B + OFF_XTH);
    ushort* xtl   = (ushort*)(B + OFF_XTL);
    float*  attn  = (float*)(B + OFF_ATTN);
    float*  pmax  = (float*)(B + OFF_PMAX);

    hipLaunchKernelGGL(conv_head, dim3(NB * 32), dim3(256), 0, stream, x, head_w, a);
    hipLaunchKernelGGL(bn_stats, dim3(1), dim3(256), 0, stream, a, stats);
    hipLaunchKernelGGL(ccam_kernel, dim3(64), dim3(256), 0, stream, a, stats, bn_w, bn_b, cm, out_ccam);
    hipLaunchKernelGGL(fgbg_kernel, dim3(4096), dim3(256), 0, stream, x, cm, out_fg, out_bg);

    hipLaunchKernelGGL(split_w, dim3(1280), dim3(256), 0, stream, q_w, k_w, v_w, Whi, Wlo);
    hipLaunchKernelGGL(splitT_x, dim3(32, 32, 16), dim3(256), 0, stream, x, xth, xtl);
    hipLaunchKernelGGL(qkv_gemm, dim3(8, 10, 16), dim3(256), 0, stream,
                       Whi, Wlo, xth, xtl, q_b, k_b, v_b, qf, kf, vh, vl);
    hipLaunchKernelGGL(splitT_qk, dim3(32, 4, 32), dim3(256), 0, stream,
                       qf, kf, qth, qtl, kth, ktl);
    hipLaunchKernelGGL(score_gemm, dim3(8, 8, 16), dim3(256), 0, stream,
                       qth, qtl, kth, ktl, attn);
    hipLaunchKernelGGL(softmax_split, dim3(NB * HW), dim3(256), 0, stream, attn);
    hipLaunchKernelGGL(out_gemm, dim3(8, 8, 16), dim3(256), 0, stream,
                       vh, vl, (const ushort*)attn, x, gamma, pmax);
    hipLaunchKernelGGL(gf_reduce, dim3(64), dim3(256), 0, stream, pmax, out_gf);
}

// Round 4
// 522.872 us; speedup vs baseline: 1.3135x; 1.3135x over previous
//
#include <hip/hip_runtime.h>
#include <math.h>

typedef short bf16x8 __attribute__((ext_vector_type(8)));
typedef float f32x4 __attribute__((ext_vector_type(4)));

#define NB 16
#define CC 1024
#define HW 1024
#define CQK 128
#define EPS 1e-5f

// ---- ws byte offsets (total ~167 MiB) ----
#define OFF_A     0
#define OFF_STATS 65536
#define OFF_CM    66048
#define OFF_WHI   131584
#define OFF_WLO   (OFF_WHI + 2621440)
#define OFF_QF    (OFF_WLO + 2621440)
#define OFF_KF    (OFF_QF + 8388608)
#define OFF_QTH   (OFF_KF + 8388608)
#define OFF_QTL   (OFF_QTH + 4194304)
#define OFF_KTH   (OFF_QTL + 4194304)
#define OFF_KTL   (OFF_KTH + 4194304)
#define OFF_VH    (OFF_KTL + 4194304)
#define OFF_VL    (OFF_VH + 33554432)
#define OFF_XTH   (OFF_VL + 33554432)
#define OFF_XTL   (OFF_XTH + 33554432)
#define OFF_ATTN  OFF_XTH                    /* overlay: attn/P lives where xT was */
#define OFF_PMAX  (OFF_XTL + 33554432)
// conv partials overlay the VH region (dead until qkv_gemm runs, stream-serial)
#define OFF_YP    OFF_VH                     /* [16 n][16 cch][9 tap][1024 p] f32 = 9.4 MB */

__device__ __forceinline__ ushort bf16_rn(float f) {
    union { float f; unsigned u; } v; v.f = f;
    unsigned u = v.u;
    return (ushort)((u + 0x7FFFu + ((u >> 16) & 1u)) >> 16);
}
__device__ __forceinline__ float bf16f(ushort h) {
    union { unsigned u; float f; } v; v.u = ((unsigned)h) << 16;
    return v.f;
}
__device__ __forceinline__ void split2(float f, ushort& h, ushort& l) {
    h = bf16_rn(f);
    l = bf16_rn(f - bf16f(h));
}

// ================= conv head: 9-tap channel-reduction GEMM =================
// y_tap[n,p] = sum_c w[c,tap] * x[n,c,p]  (partials over 64-channel chunks)
__global__ __launch_bounds__(256) void conv_tap9(
        const float* __restrict__ x, const float* __restrict__ hwt,
        float* __restrict__ yp) {
    int n = blockIdx.z, cch = blockIdx.y, pix = blockIdx.x;
    int t = threadIdx.x;
    int p = (pix << 8) + t;
    int c0 = cch << 6;
    float acc[9] = {};
    const float* xp = x + ((size_t)(n * CC + c0) << 10) + p;
    const float* wp = hwt + c0 * 9;
    #pragma unroll 4
    for (int cc = 0; cc < 64; ++cc) {
        float xv = xp[(size_t)cc << 10];
        const float* w9 = wp + cc * 9;   // block-uniform -> scalar loads
        #pragma unroll
        for (int tp = 0; tp < 9; ++tp) acc[tp] += xv * w9[tp];
    }
    float* d = yp + (((size_t)(n * 16 + cch) * 9) << 10) + p;
    #pragma unroll
    for (int tp = 0; tp < 9; ++tp) d[(size_t)tp << 10] = acc[tp];
}

// a[n,h,w] = sum_tap sum_cch yp[n,cch,tap,(h+dy)*32+(w+dx)]  (zero-pad OOB)
__global__ __launch_bounds__(256) void conv_combine(
        const float* __restrict__ yp, float* __restrict__ a) {
    int idx = blockIdx.x * 256 + threadIdx.x;   // 16*1024
    int n = idx >> 10, p = idx & 1023;
    int h = p >> 5, w = p & 31;
    float s = 0.f;
    #pragma unroll
    for (int tp = 0; tp < 9; ++tp) {
        int dy = tp / 3 - 1, dx = tp % 3 - 1;
        int hh = h + dy, ww = w + dx;
        if (hh < 0 || hh > 31 || ww < 0 || ww > 31) continue;
        int pp = (hh << 5) + ww;
        const float* b = yp + ((size_t)(n * 16) * 9 << 10) + ((size_t)tp << 10) + pp;
        #pragma unroll
        for (int cch = 0; cch < 16; ++cch) s += b[((size_t)cch * 9) << 10];
    }
    a[idx] = s;
}

// ================= small kernels =================
__global__ void bn_stats(const float* __restrict__ a, float* __restrict__ stats) {
    int t = threadIdx.x;
    float s = 0.f, ss = 0.f;
    for (int i = t; i < NB * HW; i += 256) { float v = a[i]; s += v; ss += v * v; }
    __shared__ float rs[256], rss[256];
    rs[t] = s; rss[t] = ss;
    __syncthreads();
    for (int off = 128; off > 0; off >>= 1) {
        if (t < off) { rs[t] += rs[t + off]; rss[t] += rss[t + off]; }
        __syncthreads();
    }
    if (t == 0) {
        float mu = rs[0] / (NB * HW);
        float var = rss[0] / (NB * HW) - mu * mu;
        stats[0] = mu;
        stats[1] = rsqrtf(var + EPS);
    }
}

__global__ void ccam_kernel(const float* __restrict__ a, const float* __restrict__ stats,
                            const float* __restrict__ bn_w, const float* __restrict__ bn_b,
                            float* __restrict__ cm, float* __restrict__ out_ccam) {
    int i = blockIdx.x * 256 + threadIdx.x;
    float z = (a[i] - stats[0]) * stats[1] * bn_w[0] + bn_b[0];
    float sg = 1.f / (1.f + expf(-z));
    cm[i] = sg;
    out_ccam[i] = sg;
}

__global__ void fgbg_kernel(const float* __restrict__ x, const float* __restrict__ cm,
                            float* __restrict__ out_fg, float* __restrict__ out_bg) {
    int gid = blockIdx.x * blockDim.x + threadIdx.x;
    int wid = gid >> 6;
    int lane = threadIdx.x & 63;
    int n = wid >> 10, c = wid & 1023;
    const float* xp = x + ((size_t)(n * CC + c) << 10);
    const float* cp = cm + (n << 10);
    float sf = 0.f, sa = 0.f;
    for (int h = lane; h < HW; h += 64) { float xv = xp[h]; sf += cp[h] * xv; sa += xv; }
    for (int off = 32; off > 0; off >>= 1) { sf += __shfl_xor(sf, off); sa += __shfl_xor(sa, off); }
    if (lane == 0) {
        float fgv = sf * (1.f / HW);
        out_fg[(n << 10) + c] = fgv;
        out_bg[(n << 10) + c] = sa * (1.f / HW) - fgv;
    }
}

// ================= split / transpose pre-passes =================
__global__ void split_w(const float* __restrict__ qw, const float* __restrict__ kw,
                        const float* __restrict__ vw,
                        ushort* __restrict__ wh, ushort* __restrict__ wl) {
    size_t e = ((size_t)blockIdx.x * 256 + threadIdx.x) * 4;
    float4 v;
    if (e < 131072)       v = *(const float4*)(qw + e);
    else if (e < 262144)  v = *(const float4*)(kw + e - 131072);
    else                  v = *(const float4*)(vw + e - 262144);
    ushort4 h4, l4;
    split2(v.x, h4.x, l4.x); split2(v.y, h4.y, l4.y);
    split2(v.z, h4.z, l4.z); split2(v.w, h4.w, l4.w);
    *(ushort4*)&wh[e] = h4;
    *(ushort4*)&wl[e] = l4;
}

__global__ void splitT_x(const float* __restrict__ x,
                         ushort* __restrict__ xh, ushort* __restrict__ xl) {
    int n = blockIdx.z, cb = blockIdx.y, hb = blockIdx.x;
    __shared__ float tile[32][33];
    int t = threadIdx.x;
    int r = t >> 3, c4 = (t & 7) << 2;
    const float* s = x + ((size_t)(n * CC + cb * 32 + r) << 10) + hb * 32 + c4;
    float4 v = *(const float4*)s;
    tile[r][c4] = v.x; tile[r][c4 + 1] = v.y; tile[r][c4 + 2] = v.z; tile[r][c4 + 3] = v.w;
    __syncthreads();
    int hw_l = t >> 3, cg = (t & 7) << 2;
    float f0 = tile[cg + 0][hw_l], f1 = tile[cg + 1][hw_l];
    float f2 = tile[cg + 2][hw_l], f3 = tile[cg + 3][hw_l];
    ushort4 h4, l4;
    split2(f0, h4.x, l4.x); split2(f1, h4.y, l4.y);
    split2(f2, h4.z, l4.z); split2(f3, h4.w, l4.w);
    size_t di = ((size_t)(n * HW + hb * 32 + hw_l) << 10) + cb * 32 + cg;
    *(ushort4*)&xh[di] = h4;
    *(ushort4*)&xl[di] = l4;
}

__global__ void splitT_qk(const float* __restrict__ qf, const float* __restrict__ kf,
                          ushort* __restrict__ qth, ushort* __restrict__ qtl,
                          ushort* __restrict__ kth, ushort* __restrict__ ktl) {
    int z = blockIdx.z;
    int n = z >> 1, which = z & 1;
    const float* src = which ? kf : qf;
    ushort* dh = which ? kth : qth;
    ushort* dl = which ? ktl : qtl;
    int ob = blockIdx.y, hb = blockIdx.x;
    __shared__ float tile[32][33];
    int t = threadIdx.x;
    int r = t >> 3, c4 = (t & 7) << 2;
    const float* s = src + ((size_t)(n * CQK + ob * 32 + r) << 10) + hb * 32 + c4;
    float4 v = *(const float4*)s;
    tile[r][c4] = v.x; tile[r][c4 + 1] = v.y; tile[r][c4 + 2] = v.z; tile[r][c4 + 3] = v.w;
    __syncthreads();
    int hw_l = t >> 3, og = (t & 7) << 2;
    float f0 = tile[og + 0][hw_l], f1 = tile[og + 1][hw_l];
    float f2 = tile[og + 2][hw_l], f3 = tile[og + 3][hw_l];
    ushort4 h4, l4;
    split2(f0, h4.x, l4.x); split2(f1, h4.y, l4.y);
    split2(f2, h4.z, l4.z); split2(f3, h4.w, l4.w);
    size_t di = ((size_t)(n * HW + hb * 32 + hw_l) << 7) + ob * 32 + og;
    *(ushort4*)&dh[di] = h4;
    *(ushort4*)&dl[di] = l4;
}

// ================= split-bf16 MFMA GEMM core =================
__device__ __forceinline__ void split_gemm_loop(
        const ushort* __restrict__ Ah_g, const ushort* __restrict__ Al_g, int ap,
        const ushort* __restrict__ Bh_g, const ushort* __restrict__ Bl_g, int bp,
        int K, ushort* lds, f32x4 acc[4][4]) {
    const int t = threadIdx.x;
    const int lane = t & 63, wid = t >> 6;
    const int lr = lane & 15, kg = lane >> 4;
    const int wm = (wid >> 1) << 6, wn = (wid & 1) << 6;
    ushort* Ah = lds;
    ushort* Al = lds + 5120;
    ushort* Bh = lds + 10240;
    ushort* Bl = lds + 15360;
    const int r_ = t >> 1, ch_ = (t & 1) << 4;
    const int lo = r_ * 40 + ch_;
    for (int k0 = 0; k0 < K; k0 += 32) {
        __syncthreads();
        {
            const ushort* g0 = Ah_g + (size_t)r_ * ap + k0 + ch_;
            const ushort* g1 = Al_g + (size_t)r_ * ap + k0 + ch_;
            const ushort* g2 = Bh_g + (size_t)r_ * bp + k0 + ch_;
            const ushort* g3 = Bl_g + (size_t)r_ * bp + k0 + ch_;
            *(uint4*)&Ah[lo]     = *(const uint4*)g0;
            *(uint4*)&Ah[lo + 8] = *(const uint4*)(g0 + 8);
            *(uint4*)&Al[lo]     = *(const uint4*)g1;
            *(uint4*)&Al[lo + 8] = *(const uint4*)(g1 + 8);
            *(uint4*)&Bh[lo]     = *(const uint4*)g2;
            *(uint4*)&Bh[lo + 8] = *(const uint4*)(g2 + 8);
            *(uint4*)&Bl[lo]     = *(const uint4*)g3;
            *(uint4*)&Bl[lo + 8] = *(const uint4*)(g3 + 8);
        }
        __syncthreads();
        bf16x8 ah[4], al[4], bh[4], bl[4];
        #pragma unroll
        for (int i = 0; i < 4; ++i) {
            ah[i] = *(const bf16x8*)&Ah[(wm + i * 16 + lr) * 40 + kg * 8];
            al[i] = *(const bf16x8*)&Al[(wm + i * 16 + lr) * 40 + kg * 8];
            bh[i] = *(const bf16x8*)&Bh[(wn + i * 16 + lr) * 40 + kg * 8];
            bl[i] = *(const bf16x8*)&Bl[(wn + i * 16 + lr) * 40 + kg * 8];
        }
        #pragma unroll
        for (int i = 0; i < 4; ++i)
            #pragma unroll
            for (int j = 0; j < 4; ++j) {
                acc[i][j] = __builtin_amdgcn_mfma_f32_16x16x32_bf16(ah[i], bh[j], acc[i][j], 0, 0, 0);
                acc[i][j] = __builtin_amdgcn_mfma_f32_16x16x32_bf16(ah[i], bl[j], acc[i][j], 0, 0, 0);
                acc[i][j] = __builtin_amdgcn_mfma_f32_16x16x32_bf16(al[i], bh[j], acc[i][j], 0, 0, 0);
            }
    }
}

__global__ __launch_bounds__(256) void qkv_gemm(
        const ushort* __restrict__ Whi, const ushort* __restrict__ Wlo,
        const ushort* __restrict__ xth, const ushort* __restrict__ xtl,
        const float* __restrict__ qb, const float* __restrict__ kb,
        const float* __restrict__ vb,
        float* __restrict__ qf, float* __restrict__ kf,
        ushort* __restrict__ vh, ushort* __restrict__ vl) {
    __shared__ ushort lds[20480];
    int n = blockIdx.z, m0 = blockIdx.y << 7, j0 = blockIdx.x << 7;
    f32x4 acc[4][4];
    #pragma unroll
    for (int i = 0; i < 4; ++i)
        #pragma unroll
        for (int j = 0; j < 4; ++j) acc[i][j] = (f32x4){0.f, 0.f, 0.f, 0.f};
    split_gemm_loop(Whi + (size_t)m0 * CC, Wlo + (size_t)m0 * CC, CC,
                    xth + ((size_t)(n * HW + j0)) * CC, xtl + ((size_t)(n * HW + j0)) * CC, CC,
                    CC, lds, acc);
    const int t = threadIdx.x, lane = t & 63, wid = t >> 6;
    const int lr = lane & 15, kg = lane >> 4;
    const int wm = (wid >> 1) << 6, wn = (wid & 1) << 6;
    if (m0 < 256) {
        float* dst = (m0 == 0) ? qf : kf;
        const float* bp = (m0 == 0) ? qb : kb;
        #pragma unroll
        for (int mi = 0; mi < 4; ++mi)
            #pragma unroll
            for (int r = 0; r < 4; ++r) {
                int m = wm + mi * 16 + kg * 4 + r;
                float bias = bp[m];
                #pragma unroll
                for (int nj = 0; nj < 4; ++nj) {
                    int j = j0 + wn + nj * 16 + lr;
                    dst[((size_t)(n * CQK + m) << 10) + j] = acc[mi][nj][r] + bias;
                }
            }
    } else {
        int mo = m0 - 256;
        #pragma unroll
        for (int mi = 0; mi < 4; ++mi)
            #pragma unroll
            for (int r = 0; r < 4; ++r) {
                int m = mo + wm + mi * 16 + kg * 4 + r;
                float bias = vb[m];
                #pragma unroll
                for (int nj = 0; nj < 4; ++nj) {
                    int j = j0 + wn + nj * 16 + lr;
                    float val = acc[mi][nj][r] + bias;
                    ushort h, l; split2(val, h, l);
                    size_t idx = ((size_t)(n * CC + m) << 10) + j;
                    vh[idx] = h; vl[idx] = l;
                }
            }
    }
}

__global__ __launch_bounds__(256) void score_gemm(
        const ushort* __restrict__ qth, const ushort* __restrict__ qtl,
        const ushort* __restrict__ kth, const ushort* __restrict__ ktl,
        float* __restrict__ attn) {
    __shared__ ushort lds[20480];
    int n = blockIdx.z, i0 = blockIdx.y << 7, j0 = blockIdx.x << 7;
    f32x4 acc[4][4];
    #pragma unroll
    for (int i = 0; i < 4; ++i)
        #pragma unroll
        for (int j = 0; j < 4; ++j) acc[i][j] = (f32x4){0.f, 0.f, 0.f, 0.f};
    split_gemm_loop(qth + ((size_t)(n * HW + i0)) * CQK, qtl + ((size_t)(n * HW + i0)) * CQK, CQK,
                    kth + ((size_t)(n * HW + j0)) * CQK, ktl + ((size_t)(n * HW + j0)) * CQK, CQK,
                    CQK, lds, acc);
    const int t = threadIdx.x, lane = t & 63, wid = t >> 6;
    const int lr = lane & 15, kg = lane >> 4;
    const int wm = (wid >> 1) << 6, wn = (wid & 1) << 6;
    #pragma unroll
    for (int mi = 0; mi < 4; ++mi)
        #pragma unroll
        for (int r = 0; r < 4; ++r) {
            int irow = i0 + wm + mi * 16 + kg * 4 + r;
            #pragma unroll
            for (int nj = 0; nj < 4; ++nj) {
                int j = j0 + wn + nj * 16 + lr;
                attn[((size_t)(n * HW + irow) << 10) + j] = acc[mi][nj][r];
            }
        }
}

__global__ void softmax_split(float* __restrict__ attn) {
    int row = blockIdx.x;
    float* p = attn + ((size_t)row << 10);
    int t = threadIdx.x;
    int wid = t >> 6, lane = t & 63;
    float vals[4];
    float m = -INFINITY;
    #pragma unroll
    for (int r = 0; r < 4; ++r) { vals[r] = p[t + (r << 8)]; m = fmaxf(m, vals[r]); }
    for (int off = 32; off > 0; off >>= 1) m = fmaxf(m, __shfl_xor(m, off));
    __shared__ float redm[4], reds[4];
    if (lane == 0) redm[wid] = m;
    __syncthreads();
    if (t == 0) {
        float mm = redm[0];
        for (int g = 1; g < 4; ++g) mm = fmaxf(mm, redm[g]);
        redm[0] = mm;
    }
    __syncthreads();
    m = redm[0];
    float s = 0.f;
    #pragma unroll
    for (int r = 0; r < 4; ++r) { vals[r] = expf(vals[r] - m); s += vals[r]; }
    for (int off = 32; off > 0; off >>= 1) s += __shfl_xor(s, off);
    if (lane == 0) reds[wid] = s;
    __syncthreads();
    if (t == 0) {
        float ss = reds[0];
        for (int g = 1; g < 4; ++g) ss += reds[g];
        reds[0] = ss;
    }
    __syncthreads();
    float inv = 1.f / reds[0];
    ushort* ph = (ushort*)p;
    #pragma unroll
    for (int r = 0; r < 4; ++r) {
        float pv = vals[r] * inv;
        ushort h, l; split2(pv, h, l);
        ph[t + (r << 8)] = h;
        ph[1024 + t + (r << 8)] = l;
    }
}

__global__ __launch_bounds__(256) void out_gemm(
        const ushort* __restrict__ vh, const ushort* __restrict__ vl,
        const ushort* __restrict__ pus,
        const float* __restrict__ x, const float* __restrict__ gamma,
        float* __restrict__ pmax) {
    __shared__ ushort lds[20480];
    __shared__ float smax[4][64];
    int n = blockIdx.z, c0 = blockIdx.y << 7, i0 = blockIdx.x << 7;
    f32x4 acc[4][4];
    #pragma unroll
    for (int i = 0; i < 4; ++i)
        #pragma unroll
        for (int j = 0; j < 4; ++j) acc[i][j] = (f32x4){0.f, 0.f, 0.f, 0.f};
    const ushort* pb = pus + ((size_t)(n * HW + i0)) * 2048;
    split_gemm_loop(vh + ((size_t)(n * CC + c0) << 10), vl + ((size_t)(n * CC + c0) << 10), HW,
                    pb, pb + 1024, 2048,
                    HW, lds, acc);
    const int t = threadIdx.x, lane = t & 63, wid = t >> 6;
    const int lr = lane & 15, kg = lane >> 4;
    const int wm = (wid >> 1) << 6, wn = (wid & 1) << 6;
    float g = gamma[0];
    #pragma unroll
    for (int mi = 0; mi < 4; ++mi)
        #pragma unroll
        for (int r = 0; r < 4; ++r) {
            int c = c0 + wm + mi * 16 + kg * 4 + r;
            const float* xp = x + ((size_t)(n * CC + c) << 10);
            float mx = -INFINITY;
            #pragma unroll
            for (int nj = 0; nj < 4; ++nj) {
                int i = i0 + wn + nj * 16 + lr;
                mx = fmaxf(mx, g * acc[mi][nj][r] + xp[i]);
            }
            #pragma unroll
            for (int off = 1; off < 16; off <<= 1) mx = fmaxf(mx, __shfl_xor(mx, off));
            if (lr == 0) smax[wid][mi * 16 + kg * 4 + r] = mx;
        }
    __syncthreads();
    if (t < 128) {
        int half = t >> 6, cl = t & 63;
        float m = fmaxf(smax[half * 2][cl], smax[half * 2 + 1][cl]);
        pmax[((size_t)(n * 8 + blockIdx.x) << 10) + c0 + half * 64 + cl] = m;
    }
}

__global__ void gf_reduce(const float* __restrict__ pmax, float* __restrict__ gf) {
    int idx = blockIdx.x * 256 + threadIdx.x;
    int n = idx >> 10, c = idx & 1023;
    float m = -INFINITY;
    #pragma unroll
    for (int ib = 0; ib < 8; ++ib)
        m = fmaxf(m, pmax[(((size_t)(n << 3) + ib) << 10) + c]);
    gf[idx] = m;
}

extern "C" void kernel_launch(void* const* d_in, const int* in_sizes, int n_in,
                              void* d_out, int out_size, void* d_ws, size_t ws_size,
                              hipStream_t stream) {
    const float* x      = (const float*)d_in[0];
    const float* head_w = (const float*)d_in[1];
    const float* bn_w   = (const float*)d_in[2];
    const float* bn_b   = (const float*)d_in[3];
    const float* q_w    = (const float*)d_in[4];
    const float* q_b    = (const float*)d_in[5];
    const float* k_w    = (const float*)d_in[6];
    const float* k_b    = (const float*)d_in[7];
    const float* v_w    = (const float*)d_in[8];
    const float* v_b    = (const float*)d_in[9];
    const float* gamma  = (const float*)d_in[10];

    float* out      = (float*)d_out;
    float* out_fg   = out;
    float* out_bg   = out + 16384;
    float* out_ccam = out + 32768;
    float* out_gf   = out + 49152;

    char* B = (char*)d_ws;
    float*  a     = (float*)(B + OFF_A);
    float*  stats = (float*)(B + OFF_STATS);
    float*  cm    = (float*)(B + OFF_CM);
    ushort* Whi   = (ushort*)(B + OFF_WHI);
    ushort* Wlo   = (ushort*)(B + OFF_WLO);
    float*  qf    = (float*)(B + OFF_QF);
    float*  kf    = (float*)(B + OFF_KF);
    ushort* qth   = (ushort*)(B + OFF_QTH);
    ushort* qtl   = (ushort*)(B + OFF_QTL);
    ushort* kth   = (ushort*)(B + OFF_KTH);
    ushort* ktl   = (ushort*)(B + OFF_KTL);
    ushort* vh    = (ushort*)(B + OFF_VH);
    ushort* vl    = (ushort*)(B + OFF_VL);
    ushort* xth   = (ushort*)(B + OFF_XTH);
    ushort* xtl   = (ushort*)(B + OFF_XTL);
    float*  attn  = (float*)(B + OFF_ATTN);
    float*  pmax  = (float*)(B + OFF_PMAX);
    float*  ypart = (float*)(B + OFF_YP);

    hipLaunchKernelGGL(conv_tap9, dim3(4, 16, 16), dim3(256), 0, stream, x, head_w, ypart);
    hipLaunchKernelGGL(conv_combine, dim3(64), dim3(256), 0, stream, ypart, a);
    hipLaunchKernelGGL(bn_stats, dim3(1), dim3(256), 0, stream, a, stats);
    hipLaunchKernelGGL(ccam_kernel, dim3(64), dim3(256), 0, stream, a, stats, bn_w, bn_b, cm, out_ccam);
    hipLaunchKernelGGL(fgbg_kernel, dim3(4096), dim3(256), 0, stream, x, cm, out_fg, out_bg);

    hipLaunchKernelGGL(split_w, dim3(1280), dim3(256), 0, stream, q_w, k_w, v_w, Whi, Wlo);
    hipLaunchKernelGGL(splitT_x, dim3(32, 32, 16), dim3(256), 0, stream, x, xth, xtl);
    hipLaunchKernelGGL(qkv_gemm, dim3(8, 10, 16), dim3(256), 0, stream,
                       Whi, Wlo, xth, xtl, q_b, k_b, v_b, qf, kf, vh, vl);
    hipLaunchKernelGGL(splitT_qk, dim3(32, 4, 32), dim3(256), 0, stream,
                       qf, kf, qth, qtl, kth, ktl);
    hipLaunchKernelGGL(score_gemm, dim3(8, 8, 16), dim3(256), 0, stream,
                       qth, qtl, kth, ktl, attn);
    hipLaunchKernelGGL(softmax_split, dim3(NB * HW), dim3(256), 0, stream, attn);
    hipLaunchKernelGGL(out_gemm, dim3(8, 8, 16), dim3(256), 0, stream,
                       vh, vl, (const ushort*)attn, x, gamma, pmax);
    hipLaunchKernelGGL(gf_reduce, dim3(64), dim3(256), 0, stream, pmax, out_gf);
}

// Round 5
// 495.537 us; speedup vs baseline: 1.3859x; 1.0552x over previous
//
#include <hip/hip_runtime.h>
#include <math.h>

typedef short bf16x8 __attribute__((ext_vector_type(8)));
typedef float f32x4 __attribute__((ext_vector_type(4)));

#define NB 16
#define CC 1024
#define HW 1024
#define CQK 128
#define EPS 1e-5f

// ---- ws byte offsets (total ~167 MiB) ----
#define OFF_A     0
#define OFF_STATS 65536
#define OFF_CM    66048
#define OFF_WHI   131584
#define OFF_WLO   (OFF_WHI + 2621440)
#define OFF_QF    (OFF_WLO + 2621440)
#define OFF_KF    (OFF_QF + 8388608)
#define OFF_QTH   (OFF_KF + 8388608)
#define OFF_QTL   (OFF_QTH + 4194304)
#define OFF_KTH   (OFF_QTL + 4194304)
#define OFF_KTL   (OFF_KTH + 4194304)
#define OFF_VH    (OFF_KTL + 4194304)
#define OFF_VL    (OFF_VH + 33554432)
#define OFF_XTH   (OFF_VL + 33554432)
#define OFF_XTL   (OFF_XTH + 33554432)
#define OFF_ATTN  OFF_XTH                    /* overlay: attn/P lives where xT was */
#define OFF_PMAX  (OFF_XTL + 33554432)
#define OFF_YP    OFF_VH                     /* conv partials overlay VH (dead until qkv) */

__device__ __forceinline__ ushort bf16_rn(float f) {
    union { float f; unsigned u; } v; v.f = f;
    unsigned u = v.u;
    return (ushort)((u + 0x7FFFu + ((u >> 16) & 1u)) >> 16);
}
__device__ __forceinline__ float bf16f(ushort h) {
    union { unsigned u; float f; } v; v.u = ((unsigned)h) << 16;
    return v.f;
}
__device__ __forceinline__ void split2(float f, ushort& h, ushort& l) {
    h = bf16_rn(f);
    l = bf16_rn(f - bf16f(h));
}

// async global->LDS, 16B per lane; LDS dest = wave-uniform base + lane*16
__device__ __forceinline__ void gl_lds16(const void* g, void* s) {
    __builtin_amdgcn_global_load_lds(
        (const __attribute__((address_space(1))) void*)g,
        (__attribute__((address_space(3))) void*)s, 16, 0, 0);
}

// ================= conv head: 9-tap channel-reduction =================
__global__ __launch_bounds__(256) void conv_tap9(
        const float* __restrict__ x, const float* __restrict__ hwt,
        float* __restrict__ yp) {
    int n = blockIdx.z, cch = blockIdx.y, pix = blockIdx.x;
    int t = threadIdx.x;
    int p = (pix << 8) + t;
    int c0 = cch << 6;
    float acc[9] = {};
    const float* xp = x + ((size_t)(n * CC + c0) << 10) + p;
    const float* wp = hwt + c0 * 9;
    #pragma unroll 4
    for (int cc = 0; cc < 64; ++cc) {
        float xv = xp[(size_t)cc << 10];
        const float* w9 = wp + cc * 9;
        #pragma unroll
        for (int tp = 0; tp < 9; ++tp) acc[tp] += xv * w9[tp];
    }
    float* d = yp + (((size_t)(n * 16 + cch) * 9) << 10) + p;
    #pragma unroll
    for (int tp = 0; tp < 9; ++tp) d[(size_t)tp << 10] = acc[tp];
}

__global__ __launch_bounds__(256) void conv_combine(
        const float* __restrict__ yp, float* __restrict__ a) {
    int idx = blockIdx.x * 256 + threadIdx.x;
    int n = idx >> 10, p = idx & 1023;
    int h = p >> 5, w = p & 31;
    float s = 0.f;
    #pragma unroll
    for (int tp = 0; tp < 9; ++tp) {
        int dy = tp / 3 - 1, dx = tp % 3 - 1;
        int hh = h + dy, ww = w + dx;
        if (hh < 0 || hh > 31 || ww < 0 || ww > 31) continue;
        int pp = (hh << 5) + ww;
        const float* b = yp + ((size_t)(n * 16) * 9 << 10) + ((size_t)tp << 10) + pp;
        #pragma unroll
        for (int cch = 0; cch < 16; ++cch) s += b[((size_t)cch * 9) << 10];
    }
    a[idx] = s;
}

// ================= small kernels =================
__global__ void bn_stats(const float* __restrict__ a, float* __restrict__ stats) {
    int t = threadIdx.x;
    float s = 0.f, ss = 0.f;
    for (int i = t; i < NB * HW; i += 256) { float v = a[i]; s += v; ss += v * v; }
    __shared__ float rs[256], rss[256];
    rs[t] = s; rss[t] = ss;
    __syncthreads();
    for (int off = 128; off > 0; off >>= 1) {
        if (t < off) { rs[t] += rs[t + off]; rss[t] += rss[t + off]; }
        __syncthreads();
    }
    if (t == 0) {
        float mu = rs[0] / (NB * HW);
        float var = rss[0] / (NB * HW) - mu * mu;
        stats[0] = mu;
        stats[1] = rsqrtf(var + EPS);
    }
}

__global__ void ccam_kernel(const float* __restrict__ a, const float* __restrict__ stats,
                            const float* __restrict__ bn_w, const float* __restrict__ bn_b,
                            float* __restrict__ cm, float* __restrict__ out_ccam) {
    int i = blockIdx.x * 256 + threadIdx.x;
    float z = (a[i] - stats[0]) * stats[1] * bn_w[0] + bn_b[0];
    float sg = 1.f / (1.f + expf(-z));
    cm[i] = sg;
    out_ccam[i] = sg;
}

__global__ void fgbg_kernel(const float* __restrict__ x, const float* __restrict__ cm,
                            float* __restrict__ out_fg, float* __restrict__ out_bg) {
    int gid = blockIdx.x * blockDim.x + threadIdx.x;
    int wid = gid >> 6;
    int lane = threadIdx.x & 63;
    int n = wid >> 10, c = wid & 1023;
    const float* xp = x + ((size_t)(n * CC + c) << 10);
    const float* cp = cm + (n << 10);
    float sf = 0.f, sa = 0.f;
    for (int h = lane; h < HW; h += 64) { float xv = xp[h]; sf += cp[h] * xv; sa += xv; }
    for (int off = 32; off > 0; off >>= 1) { sf += __shfl_xor(sf, off); sa += __shfl_xor(sa, off); }
    if (lane == 0) {
        float fgv = sf * (1.f / HW);
        out_fg[(n << 10) + c] = fgv;
        out_bg[(n << 10) + c] = sa * (1.f / HW) - fgv;
    }
}

// ================= split / transpose pre-passes =================
__global__ void split_w(const float* __restrict__ qw, const float* __restrict__ kw,
                        const float* __restrict__ vw,
                        ushort* __restrict__ wh, ushort* __restrict__ wl) {
    size_t e = ((size_t)blockIdx.x * 256 + threadIdx.x) * 4;
    float4 v;
    if (e < 131072)       v = *(const float4*)(qw + e);
    else if (e < 262144)  v = *(const float4*)(kw + e - 131072);
    else                  v = *(const float4*)(vw + e - 262144);
    ushort4 h4, l4;
    split2(v.x, h4.x, l4.x); split2(v.y, h4.y, l4.y);
    split2(v.z, h4.z, l4.z); split2(v.w, h4.w, l4.w);
    *(ushort4*)&wh[e] = h4;
    *(ushort4*)&wl[e] = l4;
}

__global__ void splitT_x(const float* __restrict__ x,
                         ushort* __restrict__ xh, ushort* __restrict__ xl) {
    int n = blockIdx.z, cb = blockIdx.y, hb = blockIdx.x;
    __shared__ float tile[32][33];
    int t = threadIdx.x;
    int r = t >> 3, c4 = (t & 7) << 2;
    const float* s = x + ((size_t)(n * CC + cb * 32 + r) << 10) + hb * 32 + c4;
    float4 v = *(const float4*)s;
    tile[r][c4] = v.x; tile[r][c4 + 1] = v.y; tile[r][c4 + 2] = v.z; tile[r][c4 + 3] = v.w;
    __syncthreads();
    int hw_l = t >> 3, cg = (t & 7) << 2;
    float f0 = tile[cg + 0][hw_l], f1 = tile[cg + 1][hw_l];
    float f2 = tile[cg + 2][hw_l], f3 = tile[cg + 3][hw_l];
    ushort4 h4, l4;
    split2(f0, h4.x, l4.x); split2(f1, h4.y, l4.y);
    split2(f2, h4.z, l4.z); split2(f3, h4.w, l4.w);
    size_t di = ((size_t)(n * HW + hb * 32 + hw_l) << 10) + cb * 32 + cg;
    *(ushort4*)&xh[di] = h4;
    *(ushort4*)&xl[di] = l4;
}

__global__ void splitT_qk(const float* __restrict__ qf, const float* __restrict__ kf,
                          ushort* __restrict__ qth, ushort* __restrict__ qtl,
                          ushort* __restrict__ kth, ushort* __restrict__ ktl) {
    int z = blockIdx.z;
    int n = z >> 1, which = z & 1;
    const float* src = which ? kf : qf;
    ushort* dh = which ? kth : qth;
    ushort* dl = which ? ktl : qtl;
    int ob = blockIdx.y, hb = blockIdx.x;
    __shared__ float tile[32][33];
    int t = threadIdx.x;
    int r = t >> 3, c4 = (t & 7) << 2;
    const float* s = src + ((size_t)(n * CQK + ob * 32 + r) << 10) + hb * 32 + c4;
    float4 v = *(const float4*)s;
    tile[r][c4] = v.x; tile[r][c4 + 1] = v.y; tile[r][c4 + 2] = v.z; tile[r][c4 + 3] = v.w;
    __syncthreads();
    int hw_l = t >> 3, og = (t & 7) << 2;
    float f0 = tile[og + 0][hw_l], f1 = tile[og + 1][hw_l];
    float f2 = tile[og + 2][hw_l], f3 = tile[og + 3][hw_l];
    ushort4 h4, l4;
    split2(f0, h4.x, l4.x); split2(f1, h4.y, l4.y);
    split2(f2, h4.z, l4.z); split2(f3, h4.w, l4.w);
    size_t di = ((size_t)(n * HW + hb * 32 + hw_l) << 7) + ob * 32 + og;
    *(ushort4*)&dh[di] = h4;
    *(ushort4*)&dl[di] = l4;
}

// ================= split-bf16 MFMA GEMM core =================
// Block 128x128, 4 waves (2x2), wave tile 64x64 = 4x4 frags of 16x16, K-step 32.
// LDS: A buf = 128 rows x 128B (row = [hi 64B | lo 64B]); chunk c of row r holds
// source chunk c ^ (r&7) (XOR swizzle). Staged via global_load_lds width-16 with
// pre-swizzled per-lane global source (both-sides rule); ds_read applies same XOR.
__device__ __forceinline__ void split_gemm_loop(
        const ushort* __restrict__ Ah_g, const ushort* __restrict__ Al_g, int ap,
        const ushort* __restrict__ Bh_g, const ushort* __restrict__ Bl_g, int bp,
        int K, ushort* lds, f32x4 acc[4][4]) {
    const int t = threadIdx.x;
    const int lane = t & 63, w = t >> 6;
    const int lr = lane & 15, kg = lane >> 4;
    const int wm = (w >> 1) << 6, wn = (w & 1) << 6;
    ushort* Ab = lds;            // 8192 ushorts = 16 KB
    ushort* Bb = lds + 8192;
    // staging lane mapping (invariant across rows: row&7 == lane>>3 & 7)
    const int rowl = lane >> 3;          // 0..7
    const int cs = (lane & 7) ^ rowl;    // swizzled source chunk for this lane
    const ushort* selA = (cs < 4) ? (Ah_g + cs * 8) : (Al_g + (cs - 4) * 8);
    const ushort* selB = (cs < 4) ? (Bh_g + cs * 8) : (Bl_g + (cs - 4) * 8);
    const int rb = (w << 5) + rowl;      // this lane's staging row base
    const int ldsb = (w << 5) << 6;      // wave-uniform LDS base (ushorts)
    // read-side swizzled chunk columns
    const int cAh = kg ^ (lr & 7);
    const int cAl = (kg | 4) ^ (lr & 7);
    for (int k0 = 0; k0 < K; k0 += 32) {
        __syncthreads();
        #pragma unroll
        for (int q = 0; q < 4; ++q) {
            int r = rb + (q << 3);
            gl_lds16(selA + (size_t)r * ap + k0, Ab + ldsb + (q << 9));
            gl_lds16(selB + (size_t)r * bp + k0, Bb + ldsb + (q << 9));
        }
        __syncthreads();   // drains vmcnt -> LDS populated
        bf16x8 ah[4], al[4], bh[4], bl[4];
        #pragma unroll
        for (int i = 0; i < 4; ++i) {
            int ra = (wm + i * 16 + lr) << 6;
            int rbr = (wn + i * 16 + lr) << 6;
            ah[i] = *(const bf16x8*)&Ab[ra + cAh * 8];
            al[i] = *(const bf16x8*)&Ab[ra + cAl * 8];
            bh[i] = *(const bf16x8*)&Bb[rbr + cAh * 8];
            bl[i] = *(const bf16x8*)&Bb[rbr + cAl * 8];
        }
        #pragma unroll
        for (int i = 0; i < 4; ++i)
            #pragma unroll
            for (int j = 0; j < 4; ++j) {
                acc[i][j] = __builtin_amdgcn_mfma_f32_16x16x32_bf16(ah[i], bh[j], acc[i][j], 0, 0, 0);
                acc[i][j] = __builtin_amdgcn_mfma_f32_16x16x32_bf16(ah[i], bl[j], acc[i][j], 0, 0, 0);
                acc[i][j] = __builtin_amdgcn_mfma_f32_16x16x32_bf16(al[i], bh[j], acc[i][j], 0, 0, 0);
            }
    }
}

__global__ __launch_bounds__(256) void qkv_gemm(
        const ushort* __restrict__ Whi, const ushort* __restrict__ Wlo,
        const ushort* __restrict__ xth, const ushort* __restrict__ xtl,
        const float* __restrict__ qb, const float* __restrict__ kb,
        const float* __restrict__ vb,
        float* __restrict__ qf, float* __restrict__ kf,
        ushort* __restrict__ vh, ushort* __restrict__ vl) {
    __shared__ __align__(16) ushort lds[16384];
    int n = blockIdx.z, m0 = blockIdx.y << 7, j0 = blockIdx.x << 7;
    f32x4 acc[4][4];
    #pragma unroll
    for (int i = 0; i < 4; ++i)
        #pragma unroll
        for (int j = 0; j < 4; ++j) acc[i][j] = (f32x4){0.f, 0.f, 0.f, 0.f};
    split_gemm_loop(Whi + (size_t)m0 * CC, Wlo + (size_t)m0 * CC, CC,
                    xth + ((size_t)(n * HW + j0)) * CC, xtl + ((size_t)(n * HW + j0)) * CC, CC,
                    CC, lds, acc);
    const int t = threadIdx.x, lane = t & 63, wid = t >> 6;
    const int lr = lane & 15, kg = lane >> 4;
    const int wm = (wid >> 1) << 6, wn = (wid & 1) << 6;
    if (m0 < 256) {
        float* dst = (m0 == 0) ? qf : kf;
        const float* bp = (m0 == 0) ? qb : kb;
        #pragma unroll
        for (int mi = 0; mi < 4; ++mi)
            #pragma unroll
            for (int r = 0; r < 4; ++r) {
                int m = wm + mi * 16 + kg * 4 + r;
                float bias = bp[m];
                #pragma unroll
                for (int nj = 0; nj < 4; ++nj) {
                    int j = j0 + wn + nj * 16 + lr;
                    dst[((size_t)(n * CQK + m) << 10) + j] = acc[mi][nj][r] + bias;
                }
            }
    } else {
        int mo = m0 - 256;
        #pragma unroll
        for (int mi = 0; mi < 4; ++mi)
            #pragma unroll
            for (int r = 0; r < 4; ++r) {
                int m = mo + wm + mi * 16 + kg * 4 + r;
                float bias = vb[m];
                #pragma unroll
                for (int nj = 0; nj < 4; ++nj) {
                    int j = j0 + wn + nj * 16 + lr;
                    float val = acc[mi][nj][r] + bias;
                    ushort h, l; split2(val, h, l);
                    size_t idx = ((size_t)(n * CC + m) << 10) + j;
                    vh[idx] = h; vl[idx] = l;
                }
            }
    }
}

__global__ __launch_bounds__(256) void score_gemm(
        const ushort* __restrict__ qth, const ushort* __restrict__ qtl,
        const ushort* __restrict__ kth, const ushort* __restrict__ ktl,
        float* __restrict__ attn) {
    __shared__ __align__(16) ushort lds[16384];
    int n = blockIdx.z, i0 = blockIdx.y << 7, j0 = blockIdx.x << 7;
    f32x4 acc[4][4];
    #pragma unroll
    for (int i = 0; i < 4; ++i)
        #pragma unroll
        for (int j = 0; j < 4; ++j) acc[i][j] = (f32x4){0.f, 0.f, 0.f, 0.f};
    split_gemm_loop(qth + ((size_t)(n * HW + i0)) * CQK, qtl + ((size_t)(n * HW + i0)) * CQK, CQK,
                    kth + ((size_t)(n * HW + j0)) * CQK, ktl + ((size_t)(n * HW + j0)) * CQK, CQK,
                    CQK, lds, acc);
    const int t = threadIdx.x, lane = t & 63, wid = t >> 6;
    const int lr = lane & 15, kg = lane >> 4;
    const int wm = (wid >> 1) << 6, wn = (wid & 1) << 6;
    #pragma unroll
    for (int mi = 0; mi < 4; ++mi)
        #pragma unroll
        for (int r = 0; r < 4; ++r) {
            int irow = i0 + wm + mi * 16 + kg * 4 + r;
            #pragma unroll
            for (int nj = 0; nj < 4; ++nj) {
                int j = j0 + wn + nj * 16 + lr;
                attn[((size_t)(n * HW + irow) << 10) + j] = acc[mi][nj][r];
            }
        }
}

__global__ void softmax_split(float* __restrict__ attn) {
    int row = blockIdx.x;
    float* p = attn + ((size_t)row << 10);
    int t = threadIdx.x;
    int wid = t >> 6, lane = t & 63;
    float vals[4];
    float m = -INFINITY;
    #pragma unroll
    for (int r = 0; r < 4; ++r) { vals[r] = p[t + (r << 8)]; m = fmaxf(m, vals[r]); }
    for (int off = 32; off > 0; off >>= 1) m = fmaxf(m, __shfl_xor(m, off));
    __shared__ float redm[4], reds[4];
    if (lane == 0) redm[wid] = m;
    __syncthreads();
    if (t == 0) {
        float mm = redm[0];
        for (int g = 1; g < 4; ++g) mm = fmaxf(mm, redm[g]);
        redm[0] = mm;
    }
    __syncthreads();
    m = redm[0];
    float s = 0.f;
    #pragma unroll
    for (int r = 0; r < 4; ++r) { vals[r] = expf(vals[r] - m); s += vals[r]; }
    for (int off = 32; off > 0; off >>= 1) s += __shfl_xor(s, off);
    if (lane == 0) reds[wid] = s;
    __syncthreads();
    if (t == 0) {
        float ss = reds[0];
        for (int g = 1; g < 4; ++g) ss += reds[g];
        reds[0] = ss;
    }
    __syncthreads();
    float inv = 1.f / reds[0];
    ushort* ph = (ushort*)p;
    #pragma unroll
    for (int r = 0; r < 4; ++r) {
        float pv = vals[r] * inv;
        ushort h, l; split2(pv, h, l);
        ph[t + (r << 8)] = h;
        ph[1024 + t + (r << 8)] = l;
    }
}

__global__ __launch_bounds__(256) void out_gemm(
        const ushort* __restrict__ vh, const ushort* __restrict__ vl,
        const ushort* __restrict__ pus,
        const float* __restrict__ x, const float* __restrict__ gamma,
        float* __restrict__ pmax) {
    __shared__ __align__(16) ushort lds[16384];
    int n = blockIdx.z, c0 = blockIdx.y << 7, i0 = blockIdx.x << 7;
    f32x4 acc[4][4];
    #pragma unroll
    for (int i = 0; i < 4; ++i)
        #pragma unroll
        for (int j = 0; j < 4; ++j) acc[i][j] = (f32x4){0.f, 0.f, 0.f, 0.f};
    const ushort* pb = pus + ((size_t)(n * HW + i0)) * 2048;
    split_gemm_loop(vh + ((size_t)(n * CC + c0) << 10), vl + ((size_t)(n * CC + c0) << 10), HW,
                    pb, pb + 1024, 2048,
                    HW, lds, acc);
    const int t = threadIdx.x, lane = t & 63, wid = t >> 6;
    const int lr = lane & 15, kg = lane >> 4;
    const int wm = (wid >> 1) << 6, wn = (wid & 1) << 6;
    float g = gamma[0];
    __syncthreads();   // staging LDS is dead; reuse first 1KB for smax
    float (*smax)[64] = (float(*)[64])lds;
    #pragma unroll
    for (int mi = 0; mi < 4; ++mi)
        #pragma unroll
        for (int r = 0; r < 4; ++r) {
            int c = c0 + wm + mi * 16 + kg * 4 + r;
            const float* xp = x + ((size_t)(n * CC + c) << 10);
            float mx = -INFINITY;
            #pragma unroll
            for (int nj = 0; nj < 4; ++nj) {
                int i = i0 + wn + nj * 16 + lr;
                mx = fmaxf(mx, g * acc[mi][nj][r] + xp[i]);
            }
            #pragma unroll
            for (int off = 1; off < 16; off <<= 1) mx = fmaxf(mx, __shfl_xor(mx, off));
            if (lr == 0) smax[wid][mi * 16 + kg * 4 + r] = mx;
        }
    __syncthreads();
    if (t < 128) {
        int half = t >> 6, cl = t & 63;
        float m = fmaxf(smax[half * 2][cl], smax[half * 2 + 1][cl]);
        pmax[((size_t)(n * 8 + blockIdx.x) << 10) + c0 + half * 64 + cl] = m;
    }
}

__global__ void gf_reduce(const float* __restrict__ pmax, float* __restrict__ gf) {
    int idx = blockIdx.x * 256 + threadIdx.x;
    int n = idx >> 10, c = idx & 1023;
    float m = -INFINITY;
    #pragma unroll
    for (int ib = 0; ib < 8; ++ib)
        m = fmaxf(m, pmax[(((size_t)(n << 3) + ib) << 10) + c]);
    gf[idx] = m;
}

extern "C" void kernel_launch(void* const* d_in, const int* in_sizes, int n_in,
                              void* d_out, int out_size, void* d_ws, size_t ws_size,
                              hipStream_t stream) {
    const float* x      = (const float*)d_in[0];
    const float* head_w = (const float*)d_in[1];
    const float* bn_w   = (const float*)d_in[2];
    const float* bn_b   = (const float*)d_in[3];
    const float* q_w    = (const float*)d_in[4];
    const float* q_b    = (const float*)d_in[5];
    const float* k_w    = (const float*)d_in[6];
    const float* k_b    = (const float*)d_in[7];
    const float* v_w    = (const float*)d_in[8];
    const float* v_b    = (const float*)d_in[9];
    const float* gamma  = (const float*)d_in[10];

    float* out      = (float*)d_out;
    float* out_fg   = out;
    float* out_bg   = out + 16384;
    float* out_ccam = out + 32768;
    float* out_gf   = out + 49152;

    char* B = (char*)d_ws;
    float*  a     = (float*)(B + OFF_A);
    float*  stats = (float*)(B + OFF_STATS);
    float*  cm    = (float*)(B + OFF_CM);
    ushort* Whi   = (ushort*)(B + OFF_WHI);
    ushort* Wlo   = (ushort*)(B + OFF_WLO);
    float*  qf    = (float*)(B + OFF_QF);
    float*  kf    = (float*)(B + OFF_KF);
    ushort* qth   = (ushort*)(B + OFF_QTH);
    ushort* qtl   = (ushort*)(B + OFF_QTL);
    ushort* kth   = (ushort*)(B + OFF_KTH);
    ushort* ktl   = (ushort*)(B + OFF_KTL);
    ushort* vh    = (ushort*)(B + OFF_VH);
    ushort* vl    = (ushort*)(B + OFF_VL);
    ushort* xth   = (ushort*)(B + OFF_XTH);
    ushort* xtl   = (ushort*)(B + OFF_XTL);
    float*  attn  = (float*)(B + OFF_ATTN);
    float*  pmax  = (float*)(B + OFF_PMAX);
    float*  ypart = (float*)(B + OFF_YP);

    hipLaunchKernelGGL(conv_tap9, dim3(4, 16, 16), dim3(256), 0, stream, x, head_w, ypart);
    hipLaunchKernelGGL(conv_combine, dim3(64), dim3(256), 0, stream, ypart, a);
    hipLaunchKernelGGL(bn_stats, dim3(1), dim3(256), 0, stream, a, stats);
    hipLaunchKernelGGL(ccam_kernel, dim3(64), dim3(256), 0, stream, a, stats, bn_w, bn_b, cm, out_ccam);
    hipLaunchKernelGGL(fgbg_kernel, dim3(4096), dim3(256), 0, stream, x, cm, out_fg, out_bg);

    hipLaunchKernelGGL(split_w, dim3(1280), dim3(256), 0, stream, q_w, k_w, v_w, Whi, Wlo);
    hipLaunchKernelGGL(splitT_x, dim3(32, 32, 16), dim3(256), 0, stream, x, xth, xtl);
    hipLaunchKernelGGL(qkv_gemm, dim3(8, 10, 16), dim3(256), 0, stream,
                       Whi, Wlo, xth, xtl, q_b, k_b, v_b, qf, kf, vh, vl);
    hipLaunchKernelGGL(splitT_qk, dim3(32, 4, 32), dim3(256), 0, stream,
                       qf, kf, qth, qtl, kth, ktl);
    hipLaunchKernelGGL(score_gemm, dim3(8, 8, 16), dim3(256), 0, stream,
                       qth, qtl, kth, ktl, attn);
    hipLaunchKernelGGL(softmax_split, dim3(NB * HW), dim3(256), 0, stream, attn);
    hipLaunchKernelGGL(out_gemm, dim3(8, 8, 16), dim3(256), 0, stream,
                       vh, vl, (const ushort*)attn, x, gamma, pmax);
    hipLaunchKernelGGL(gf_reduce, dim3(64), dim3(256), 0, stream, pmax, out_gf);
}

// Round 6
// 349.303 us; speedup vs baseline: 1.9661x; 1.4186x over previous
//
#include <hip/hip_runtime.h>
#include <math.h>

typedef _Float16 f16x8 __attribute__((ext_vector_type(8)));
typedef float f32x4 __attribute__((ext_vector_type(4)));

#define NB 16
#define CC 1024
#define HW 1024
#define CQK 128
#define EPS 1e-5f

// ---- ws byte offsets (~112 MiB) ----
#define OFF_A     0
#define OFF_STATS 65536
#define OFF_CM    66048
#define OFF_WH    131584                    /* W fp16 [1280][1024] = 2.5 MB */
#define OFF_QT    (OFF_WH + 2621440)        /* qT fp16 [16][1024][128] = 4 MB */
#define OFF_KT    (OFF_QT + 4194304)
#define OFF_V     (OFF_KT + 4194304)        /* v fp16 [16][1024][1024] = 32 MB */
#define OFF_XH    (OFF_V + 33554432)        /* xT fp16 [16][1024][1024] = 32 MB */
#define OFF_ATTN  OFF_XH                    /* attn fp32 64 MB overlays XH (dead after qkv) */
#define OFF_PMAX  (OFF_ATTN + 67108864)
#define OFF_YP    OFF_V                     /* conv partials [16][32][9][1024] f32, dead before qkv */

__device__ __forceinline__ ushort f16b(float f) {
    union { _Float16 h; ushort u; } v;
    v.h = (_Float16)f;
    return v.u;
}

// async global->LDS, 16B/lane; LDS dest = wave-uniform base + lane*16
__device__ __forceinline__ void gl_lds16(const void* g, void* s) {
    __builtin_amdgcn_global_load_lds(
        (const __attribute__((address_space(1))) void*)g,
        (__attribute__((address_space(3))) void*)s, 16, 0, 0);
}

// ============ cvtT_x + fused conv 9-tap partials ============
__global__ __launch_bounds__(256) void cvtT_x_conv(
        const float* __restrict__ x, const float* __restrict__ hwt,
        ushort* __restrict__ xh, float* __restrict__ yp) {
    int n = blockIdx.z, cb = blockIdx.y, hb = blockIdx.x;
    __shared__ float tile[32][33];
    int t = threadIdx.x;
    int r = t >> 3, c4 = (t & 7) << 2;
    const float* s = x + ((size_t)(n * CC + cb * 32 + r) << 10) + hb * 32 + c4;
    float4 v = *(const float4*)s;
    tile[r][c4] = v.x; tile[r][c4 + 1] = v.y; tile[r][c4 + 2] = v.z; tile[r][c4 + 3] = v.w;
    __syncthreads();
    int hw_l = t >> 3, cg = (t & 7) << 2;
    ushort4 h4;
    h4.x = f16b(tile[cg + 0][hw_l]); h4.y = f16b(tile[cg + 1][hw_l]);
    h4.z = f16b(tile[cg + 2][hw_l]); h4.w = f16b(tile[cg + 3][hw_l]);
    *(ushort4*)&xh[((size_t)(n * HW + hb * 32 + hw_l) << 10) + cb * 32 + cg] = h4;
    float pacc[9] = {};
    #pragma unroll
    for (int cc = 0; cc < 4; ++cc) {
        float xv = tile[cg + cc][hw_l];
        const float* w9 = hwt + (cb * 32 + cg + cc) * 9;
        #pragma unroll
        for (int tp = 0; tp < 9; ++tp) pacc[tp] += xv * w9[tp];
    }
    #pragma unroll
    for (int off = 1; off < 8; off <<= 1)
        #pragma unroll
        for (int tp = 0; tp < 9; ++tp) pacc[tp] += __shfl_xor(pacc[tp], off);
    if ((t & 7) == 0) {
        #pragma unroll
        for (int tp = 0; tp < 9; ++tp)
            yp[(((size_t)(n * 32 + cb) * 9 + tp) << 10) + hb * 32 + hw_l] = pacc[tp];
    }
}

__global__ __launch_bounds__(256) void conv_combine(
        const float* __restrict__ yp, float* __restrict__ a) {
    int idx = blockIdx.x * 256 + threadIdx.x;
    int n = idx >> 10, p = idx & 1023;
    int h = p >> 5, w = p & 31;
    float s = 0.f;
    #pragma unroll
    for (int tp = 0; tp < 9; ++tp) {
        int dy = tp / 3 - 1, dx = tp % 3 - 1;
        int hh = h + dy, ww = w + dx;
        if (hh < 0 || hh > 31 || ww < 0 || ww > 31) continue;
        int pp = (hh << 5) + ww;
        const float* b = yp + (((size_t)(n * 32) * 9) << 10) + ((size_t)tp << 10) + pp;
        #pragma unroll
        for (int cch = 0; cch < 32; ++cch) s += b[((size_t)cch * 9) << 10];
    }
    a[idx] = s;
}

// ============ small kernels ============
__global__ void bn_stats(const float* __restrict__ a, float* __restrict__ stats) {
    int t = threadIdx.x;
    float s = 0.f, ss = 0.f;
    for (int i = t; i < NB * HW; i += 256) { float v = a[i]; s += v; ss += v * v; }
    __shared__ float rs[256], rss[256];
    rs[t] = s; rss[t] = ss;
    __syncthreads();
    for (int off = 128; off > 0; off >>= 1) {
        if (t < off) { rs[t] += rs[t + off]; rss[t] += rss[t + off]; }
        __syncthreads();
    }
    if (t == 0) {
        float mu = rs[0] / (NB * HW);
        float var = rss[0] / (NB * HW) - mu * mu;
        stats[0] = mu;
        stats[1] = rsqrtf(var + EPS);
    }
}

__global__ void ccam_kernel(const float* __restrict__ a, const float* __restrict__ stats,
                            const float* __restrict__ bn_w, const float* __restrict__ bn_b,
                            float* __restrict__ cm, float* __restrict__ out_ccam) {
    int i = blockIdx.x * 256 + threadIdx.x;
    float z = (a[i] - stats[0]) * stats[1] * bn_w[0] + bn_b[0];
    float sg = 1.f / (1.f + expf(-z));
    cm[i] = sg;
    out_ccam[i] = sg;
}

__global__ void fgbg_kernel(const float* __restrict__ x, const float* __restrict__ cm,
                            float* __restrict__ out_fg, float* __restrict__ out_bg) {
    int gid = blockIdx.x * blockDim.x + threadIdx.x;
    int wid = gid >> 6;
    int lane = threadIdx.x & 63;
    int n = wid >> 10, c = wid & 1023;
    const float* xp = x + ((size_t)(n * CC + c) << 10);
    const float* cp = cm + (n << 10);
    float sf = 0.f, sa = 0.f;
    for (int h = lane; h < HW; h += 64) { float xv = xp[h]; sf += cp[h] * xv; sa += xv; }
    for (int off = 32; off > 0; off >>= 1) { sf += __shfl_xor(sf, off); sa += __shfl_xor(sa, off); }
    if (lane == 0) {
        float fgv = sf * (1.f / HW);
        out_fg[(n << 10) + c] = fgv;
        out_bg[(n << 10) + c] = sa * (1.f / HW) - fgv;
    }
}

__global__ void cvt_w(const float* __restrict__ qw, const float* __restrict__ kw,
                      const float* __restrict__ vw, ushort* __restrict__ wh) {
    size_t e = ((size_t)blockIdx.x * 256 + threadIdx.x) * 4;
    float4 v;
    if (e < 131072)       v = *(const float4*)(qw + e);
    else if (e < 262144)  v = *(const float4*)(kw + e - 131072);
    else                  v = *(const float4*)(vw + e - 262144);
    ushort4 h4;
    h4.x = f16b(v.x); h4.y = f16b(v.y); h4.z = f16b(v.z); h4.w = f16b(v.w);
    *(ushort4*)&wh[e] = h4;
}

// ============ fp16 MFMA GEMM core (128x128 tile, BK=64, XOR-swizzled gl_lds) ============
__device__ __forceinline__ void gemm_loop_f16(
        const ushort* __restrict__ Ag, int ap,
        const ushort* __restrict__ Bg, int bp,
        int K, ushort* lds, f32x4 acc[4][4]) {
    const int t = threadIdx.x;
    const int lane = t & 63, w = t >> 6;
    const int lr = lane & 15, kg = lane >> 4;
    const int wm = (w >> 1) << 6, wn = (w & 1) << 6;
    ushort* Ab = lds;            // 8192 ushorts
    ushort* Bb = lds + 8192;
    const int rowl = lane >> 3;
    const int cs = (lane & 7) ^ rowl;
    const ushort* sA = Ag + cs * 8;
    const ushort* sB = Bg + cs * 8;
    const int rb = (w << 3) + rowl;
    const int ldsb = w << 9;
    const int cA0 = kg ^ (lr & 7);
    const int cA1 = (kg | 4) ^ (lr & 7);
    for (int k0 = 0; k0 < K; k0 += 64) {
        __syncthreads();
        #pragma unroll
        for (int q = 0; q < 4; ++q) {
            int r = rb + (q << 5);
            gl_lds16(sA + (size_t)r * ap + k0, Ab + ldsb + (q << 11));
            gl_lds16(sB + (size_t)r * bp + k0, Bb + ldsb + (q << 11));
        }
        __syncthreads();
        #pragma unroll
        for (int s = 0; s < 2; ++s) {
            int ch = s ? cA1 : cA0;
            f16x8 a[4], b[4];
            #pragma unroll
            for (int i = 0; i < 4; ++i) {
                a[i] = *(const f16x8*)&Ab[((wm + i * 16 + lr) << 6) + ch * 8];
                b[i] = *(const f16x8*)&Bb[((wn + i * 16 + lr) << 6) + ch * 8];
            }
            #pragma unroll
            for (int i = 0; i < 4; ++i)
                #pragma unroll
                for (int j = 0; j < 4; ++j)
                    acc[i][j] = __builtin_amdgcn_mfma_f32_16x16x32_f16(a[i], b[j], acc[i][j], 0, 0, 0);
        }
    }
}

__global__ __launch_bounds__(256) void qkv_f16(
        const ushort* __restrict__ Wh, const ushort* __restrict__ xh,
        const float* __restrict__ qb, const float* __restrict__ kb,
        const float* __restrict__ vb,
        ushort* __restrict__ qt, ushort* __restrict__ kt, ushort* __restrict__ v) {
    __shared__ __align__(16) ushort lds[17408];
    int n = blockIdx.z, m0 = blockIdx.y << 7, j0 = blockIdx.x << 7;
    f32x4 acc[4][4];
    #pragma unroll
    for (int i = 0; i < 4; ++i)
        #pragma unroll
        for (int j = 0; j < 4; ++j) acc[i][j] = (f32x4){0.f, 0.f, 0.f, 0.f};
    gemm_loop_f16(Wh + (size_t)m0 * CC, CC,
                  xh + ((size_t)(n * HW + j0)) * CC, CC, CC, lds, acc);
    const int t = threadIdx.x, lane = t & 63, wid = t >> 6;
    const int lr = lane & 15, kg = lane >> 4;
    const int wm = (wid >> 1) << 6, wn = (wid & 1) << 6;
    if (m0 < 256) {
        ushort* dst = (m0 == 0) ? qt : kt;
        const float* bp = (m0 == 0) ? qb : kb;
        #pragma unroll
        for (int mi = 0; mi < 4; ++mi)
            #pragma unroll
            for (int nj = 0; nj < 4; ++nj) {
                int m = wm + mi * 16 + kg * 4;
                int j = j0 + wn + nj * 16 + lr;
                ushort4 pk;
                pk.x = f16b(acc[mi][nj][0] + bp[m + 0]);
                pk.y = f16b(acc[mi][nj][1] + bp[m + 1]);
                pk.z = f16b(acc[mi][nj][2] + bp[m + 2]);
                pk.w = f16b(acc[mi][nj][3] + bp[m + 3]);
                *(ushort4*)&dst[((size_t)(n * HW + j) << 7) + m] = pk;
            }
    } else {
        int mo = m0 - 256;
        __syncthreads();
        #pragma unroll
        for (int mi = 0; mi < 4; ++mi)
            #pragma unroll
            for (int nj = 0; nj < 4; ++nj) {
                int ml = wm + mi * 16 + kg * 4;
                int jl = wn + nj * 16 + lr;
                #pragma unroll
                for (int r = 0; r < 4; ++r)
                    lds[(ml + r) * 136 + jl] = f16b(acc[mi][nj][r] + vb[mo + ml + r]);
            }
        __syncthreads();
        #pragma unroll
        for (int p = 0; p < 8; ++p) {
            int row = (t >> 4) + p * 16;
            int ch = (t & 15) * 8;
            *(uint4*)&v[((size_t)(n * CC + mo + row) << 10) + j0 + ch] =
                *(const uint4*)&lds[row * 136 + ch];
        }
    }
}

__global__ __launch_bounds__(256) void score_f16(
        const ushort* __restrict__ qt, const ushort* __restrict__ kt,
        float* __restrict__ attn) {
    __shared__ __align__(16) ushort lds[16384];
    int n = blockIdx.z, i0 = blockIdx.y << 7, j0 = blockIdx.x << 7;
    f32x4 acc[4][4];
    #pragma unroll
    for (int i = 0; i < 4; ++i)
        #pragma unroll
        for (int j = 0; j < 4; ++j) acc[i][j] = (f32x4){0.f, 0.f, 0.f, 0.f};
    gemm_loop_f16(qt + ((size_t)(n * HW + i0)) * CQK, CQK,
                  kt + ((size_t)(n * HW + j0)) * CQK, CQK, CQK, lds, acc);
    const int t = threadIdx.x, lane = t & 63, wid = t >> 6;
    const int lr = lane & 15, kg = lane >> 4;
    const int wm = (wid >> 1) << 6, wn = (wid & 1) << 6;
    #pragma unroll
    for (int mi = 0; mi < 4; ++mi)
        #pragma unroll
        for (int r = 0; r < 4; ++r) {
            int irow = i0 + wm + mi * 16 + kg * 4 + r;
            #pragma unroll
            for (int nj = 0; nj < 4; ++nj) {
                int j = j0 + wn + nj * 16 + lr;
                attn[((size_t)(n * HW + irow) << 10) + j] = acc[mi][nj][r];
            }
        }
}

__global__ void softmax_f16(float* __restrict__ attn) {
    int row = blockIdx.x;
    float* p = attn + ((size_t)row << 10);
    int t = threadIdx.x;
    int wid = t >> 6, lane = t & 63;
    float vals[4];
    float m = -INFINITY;
    #pragma unroll
    for (int r = 0; r < 4; ++r) { vals[r] = p[t + (r << 8)]; m = fmaxf(m, vals[r]); }
    for (int off = 32; off > 0; off >>= 1) m = fmaxf(m, __shfl_xor(m, off));
    __shared__ float redm[4], reds[4];
    if (lane == 0) redm[wid] = m;
    __syncthreads();
    if (t == 0) {
        float mm = redm[0];
        for (int g = 1; g < 4; ++g) mm = fmaxf(mm, redm[g]);
        redm[0] = mm;
    }
    __syncthreads();
    m = redm[0];
    float s = 0.f;
    #pragma unroll
    for (int r = 0; r < 4; ++r) { vals[r] = expf(vals[r] - m); s += vals[r]; }
    for (int off = 32; off > 0; off >>= 1) s += __shfl_xor(s, off);
    if (lane == 0) reds[wid] = s;
    __syncthreads();
    if (t == 0) {
        float ss = reds[0];
        for (int g = 1; g < 4; ++g) ss += reds[g];
        reds[0] = ss;
    }
    __syncthreads();
    float inv = 1.f / reds[0];
    ushort* ph = (ushort*)p;
    #pragma unroll
    for (int r = 0; r < 4; ++r) ph[t + (r << 8)] = f16b(vals[r] * inv);
}

__global__ __launch_bounds__(256) void out_f16(
        const ushort* __restrict__ v, const ushort* __restrict__ pus,
        const float* __restrict__ x, const float* __restrict__ gamma,
        float* __restrict__ pmax) {
    __shared__ __align__(16) ushort lds[16384];
    int n = blockIdx.z, c0 = blockIdx.y << 7, i0 = blockIdx.x << 7;
    f32x4 acc[4][4];
    #pragma unroll
    for (int i = 0; i < 4; ++i)
        #pragma unroll
        for (int j = 0; j < 4; ++j) acc[i][j] = (f32x4){0.f, 0.f, 0.f, 0.f};
    gemm_loop_f16(v + ((size_t)(n * CC + c0) << 10), HW,
                  pus + ((size_t)(n * HW + i0)) * 2048, 2048, HW, lds, acc);
    const int t = threadIdx.x, lane = t & 63, wid = t >> 6;
    const int lr = lane & 15, kg = lane >> 4;
    const int wm = (wid >> 1) << 6, wn = (wid & 1) << 6;
    float g = gamma[0];
    __syncthreads();
    float (*smax)[64] = (float(*)[64])lds;
    #pragma unroll
    for (int mi = 0; mi < 4; ++mi)
        #pragma unroll
        for (int r = 0; r < 4; ++r) {
            int c = c0 + wm + mi * 16 + kg * 4 + r;
            const float* xp = x + ((size_t)(n * CC + c) << 10);
            float mx = -INFINITY;
            #pragma unroll
            for (int nj = 0; nj < 4; ++nj) {
                int i = i0 + wn + nj * 16 + lr;
                mx = fmaxf(mx, g * acc[mi][nj][r] + xp[i]);
            }
            #pragma unroll
            for (int off = 1; off < 16; off <<= 1) mx = fmaxf(mx, __shfl_xor(mx, off));
            if (lr == 0) smax[wid][mi * 16 + kg * 4 + r] = mx;
        }
    __syncthreads();
    if (t < 128) {
        int half = t >> 6, cl = t & 63;
        float m = fmaxf(smax[half * 2][cl], smax[half * 2 + 1][cl]);
        pmax[((size_t)(n * 8 + blockIdx.x) << 10) + c0 + half * 64 + cl] = m;
    }
}

__global__ void gf_reduce(const float* __restrict__ pmax, float* __restrict__ gf) {
    int idx = blockIdx.x * 256 + threadIdx.x;
    int n = idx >> 10, c = idx & 1023;
    float m = -INFINITY;
    #pragma unroll
    for (int ib = 0; ib < 8; ++ib)
        m = fmaxf(m, pmax[(((size_t)(n << 3) + ib) << 10) + c]);
    gf[idx] = m;
}

extern "C" void kernel_launch(void* const* d_in, const int* in_sizes, int n_in,
                              void* d_out, int out_size, void* d_ws, size_t ws_size,
                              hipStream_t stream) {
    const float* x      = (const float*)d_in[0];
    const float* head_w = (const float*)d_in[1];
    const float* bn_w   = (const float*)d_in[2];
    const float* bn_b   = (const float*)d_in[3];
    const float* q_w    = (const float*)d_in[4];
    const float* q_b    = (const float*)d_in[5];
    const float* k_w    = (const float*)d_in[6];
    const float* k_b    = (const float*)d_in[7];
    const float* v_w    = (const float*)d_in[8];
    const float* v_b    = (const float*)d_in[9];
    const float* gamma  = (const float*)d_in[10];

    float* out      = (float*)d_out;
    float* out_fg   = out;
    float* out_bg   = out + 16384;
    float* out_ccam = out + 32768;
    float* out_gf   = out + 49152;

    char* B = (char*)d_ws;
    float*  a     = (float*)(B + OFF_A);
    float*  stats = (float*)(B + OFF_STATS);
    float*  cm    = (float*)(B + OFF_CM);
    ushort* Wh    = (ushort*)(B + OFF_WH);
    ushort* qt    = (ushort*)(B + OFF_QT);
    ushort* kt    = (ushort*)(B + OFF_KT);
    ushort* v     = (ushort*)(B + OFF_V);
    ushort* xh    = (ushort*)(B + OFF_XH);
    float*  attn  = (float*)(B + OFF_ATTN);
    float*  pmax  = (float*)(B + OFF_PMAX);
    float*  ypart = (float*)(B + OFF_YP);

    hipLaunchKernelGGL(cvtT_x_conv, dim3(32, 32, 16), dim3(256), 0, stream, x, head_w, xh, ypart);
    hipLaunchKernelGGL(conv_combine, dim3(64), dim3(256), 0, stream, ypart, a);
    hipLaunchKernelGGL(bn_stats, dim3(1), dim3(256), 0, stream, a, stats);
    hipLaunchKernelGGL(ccam_kernel, dim3(64), dim3(256), 0, stream, a, stats, bn_w, bn_b, cm, out_ccam);
    hipLaunchKernelGGL(fgbg_kernel, dim3(4096), dim3(256), 0, stream, x, cm, out_fg, out_bg);

    hipLaunchKernelGGL(cvt_w, dim3(1280), dim3(256), 0, stream, q_w, k_w, v_w, Wh);
    hipLaunchKernelGGL(qkv_f16, dim3(8, 10, 16), dim3(256), 0, stream,
                       Wh, xh, q_b, k_b, v_b, qt, kt, v);
    hipLaunchKernelGGL(score_f16, dim3(8, 8, 16), dim3(256), 0, stream, qt, kt, attn);
    hipLaunchKernelGGL(softmax_f16, dim3(NB * HW), dim3(256), 0, stream, attn);
    hipLaunchKernelGGL(out_f16, dim3(8, 8, 16), dim3(256), 0, stream,
                       v, (const ushort*)attn, x, gamma, pmax);
    hipLaunchKernelGGL(gf_reduce, dim3(64), dim3(256), 0, stream, pmax, out_gf);
}

// Round 8
// 336.711 us; speedup vs baseline: 2.0396x; 1.0374x over previous
//
#include <hip/hip_runtime.h>
#include <math.h>

typedef _Float16 f16x8 __attribute__((ext_vector_type(8)));
typedef float f32x4 __attribute__((ext_vector_type(4)));

#define NB 16
#define CC 1024
#define HW 1024
#define CQK 128
#define EPS 1e-5f

// ---- ws byte offsets (~112 MiB) ----
#define OFF_A     0
#define OFF_STATS 65536
#define OFF_CM    66048
#define OFF_WH    131584                    /* W fp16 [1280][1024] = 2.5 MB */
#define OFF_QT    (OFF_WH + 2621440)        /* qT fp16 [16][1024][128] = 4 MB */
#define OFF_KT    (OFF_QT + 4194304)
#define OFF_V     (OFF_KT + 4194304)        /* v fp16 [16][1024][1024] = 32 MB */
#define OFF_XH    (OFF_V + 33554432)        /* xT fp16 [16][1024][1024] = 32 MB */
#define OFF_ATTN  OFF_XH                    /* attn fp32 64 MB overlays XH (dead after qkv) */
#define OFF_PMAX  (OFF_ATTN + 67108864)
#define OFF_YP    OFF_V                     /* conv partials, dead before qkv */

__device__ __forceinline__ ushort f16b(float f) {
    union { _Float16 h; ushort u; } v;
    v.h = (_Float16)f;
    return v.u;
}

// async global->LDS, 16B/lane; LDS dest = wave-uniform base + lane*16
__device__ __forceinline__ void gl_lds16(const void* g, void* s) {
    __builtin_amdgcn_global_load_lds(
        (const __attribute__((address_space(1))) void*)g,
        (__attribute__((address_space(3))) void*)s, 16, 0, 0);
}

// ============ cvtT_x + fused conv 9-tap partials ============
__global__ __launch_bounds__(256) void cvtT_x_conv(
        const float* __restrict__ x, const float* __restrict__ hwt,
        ushort* __restrict__ xh, float* __restrict__ yp) {
    int n = blockIdx.z, cb = blockIdx.y, hb = blockIdx.x;
    __shared__ float tile[32][33];
    int t = threadIdx.x;
    int r = t >> 3, c4 = (t & 7) << 2;
    const float* s = x + ((size_t)(n * CC + cb * 32 + r) << 10) + hb * 32 + c4;
    float4 v = *(const float4*)s;
    tile[r][c4] = v.x; tile[r][c4 + 1] = v.y; tile[r][c4 + 2] = v.z; tile[r][c4 + 3] = v.w;
    __syncthreads();
    int hw_l = t >> 3, cg = (t & 7) << 2;
    ushort4 h4;
    h4.x = f16b(tile[cg + 0][hw_l]); h4.y = f16b(tile[cg + 1][hw_l]);
    h4.z = f16b(tile[cg + 2][hw_l]); h4.w = f16b(tile[cg + 3][hw_l]);
    *(ushort4*)&xh[((size_t)(n * HW + hb * 32 + hw_l) << 10) + cb * 32 + cg] = h4;
    float pacc[9] = {};
    #pragma unroll
    for (int cc = 0; cc < 4; ++cc) {
        float xv = tile[cg + cc][hw_l];
        const float* w9 = hwt + (cb * 32 + cg + cc) * 9;
        #pragma unroll
        for (int tp = 0; tp < 9; ++tp) pacc[tp] += xv * w9[tp];
    }
    #pragma unroll
    for (int off = 1; off < 8; off <<= 1)
        #pragma unroll
        for (int tp = 0; tp < 9; ++tp) pacc[tp] += __shfl_xor(pacc[tp], off);
    if ((t & 7) == 0) {
        #pragma unroll
        for (int tp = 0; tp < 9; ++tp)
            yp[(((size_t)(n * 32 + cb) * 9 + tp) << 10) + hb * 32 + hw_l] = pacc[tp];
    }
}

__global__ __launch_bounds__(256) void conv_combine(
        const float* __restrict__ yp, float* __restrict__ a) {
    int idx = blockIdx.x * 256 + threadIdx.x;
    int n = idx >> 10, p = idx & 1023;
    int h = p >> 5, w = p & 31;
    float s = 0.f;
    #pragma unroll
    for (int tp = 0; tp < 9; ++tp) {
        int dy = tp / 3 - 1, dx = tp % 3 - 1;
        int hh = h + dy, ww = w + dx;
        if (hh < 0 || hh > 31 || ww < 0 || ww > 31) continue;
        int pp = (hh << 5) + ww;
        const float* b = yp + (((size_t)(n * 32) * 9) << 10) + ((size_t)tp << 10) + pp;
        #pragma unroll
        for (int cch = 0; cch < 32; ++cch) s += b[((size_t)cch * 9) << 10];
    }
    a[idx] = s;
}

// ============ small kernels ============
__global__ void bn_stats(const float* __restrict__ a, float* __restrict__ stats) {
    int t = threadIdx.x;
    float s = 0.f, ss = 0.f;
    for (int i = t; i < NB * HW; i += 256) { float v = a[i]; s += v; ss += v * v; }
    __shared__ float rs[256], rss[256];
    rs[t] = s; rss[t] = ss;
    __syncthreads();
    for (int off = 128; off > 0; off >>= 1) {
        if (t < off) { rs[t] += rs[t + off]; rss[t] += rss[t + off]; }
        __syncthreads();
    }
    if (t == 0) {
        float mu = rs[0] / (NB * HW);
        float var = rss[0] / (NB * HW) - mu * mu;
        stats[0] = mu;
        stats[1] = rsqrtf(var + EPS);
    }
}

__global__ void ccam_kernel(const float* __restrict__ a, const float* __restrict__ stats,
                            const float* __restrict__ bn_w, const float* __restrict__ bn_b,
                            float* __restrict__ cm, float* __restrict__ out_ccam) {
    int i = blockIdx.x * 256 + threadIdx.x;
    float z = (a[i] - stats[0]) * stats[1] * bn_w[0] + bn_b[0];
    float sg = 1.f / (1.f + expf(-z));
    cm[i] = sg;
    out_ccam[i] = sg;
}

// fg/bg: one wave per (n,c); float4 vectorized loads (G13)
__global__ void fgbg_kernel(const float* __restrict__ x, const float* __restrict__ cm,
                            float* __restrict__ out_fg, float* __restrict__ out_bg) {
    int gid = blockIdx.x * blockDim.x + threadIdx.x;
    int wid = gid >> 6;
    int lane = threadIdx.x & 63;
    int n = wid >> 10, c = wid & 1023;
    const float4* xp = (const float4*)(x + ((size_t)(n * CC + c) << 10));
    const float4* cp = (const float4*)(cm + (n << 10));
    float sf = 0.f, sa = 0.f;
    #pragma unroll
    for (int it = 0; it < 4; ++it) {
        float4 xv = xp[lane + (it << 6)];
        float4 cv = cp[lane + (it << 6)];
        sf += xv.x * cv.x + xv.y * cv.y + xv.z * cv.z + xv.w * cv.w;
        sa += xv.x + xv.y + xv.z + xv.w;
    }
    for (int off = 32; off > 0; off >>= 1) { sf += __shfl_xor(sf, off); sa += __shfl_xor(sa, off); }
    if (lane == 0) {
        float fgv = sf * (1.f / HW);
        out_fg[(n << 10) + c] = fgv;
        out_bg[(n << 10) + c] = sa * (1.f / HW) - fgv;
    }
}

__global__ void cvt_w(const float* __restrict__ qw, const float* __restrict__ kw,
                      const float* __restrict__ vw, ushort* __restrict__ wh) {
    size_t e = ((size_t)blockIdx.x * 256 + threadIdx.x) * 4;
    float4 v;
    if (e < 131072)       v = *(const float4*)(qw + e);
    else if (e < 262144)  v = *(const float4*)(kw + e - 131072);
    else                  v = *(const float4*)(vw + e - 262144);
    ushort4 h4;
    h4.x = f16b(v.x); h4.y = f16b(v.y); h4.z = f16b(v.z); h4.w = f16b(v.w);
    *(ushort4*)&wh[e] = h4;
}

// ============ fp16 MFMA GEMM core: 128x128 tile, BK=64, XOR-swizzled gl_lds,
// 2-phase double-buffer (issue next-tile loads BEFORE computing current; one
// barrier per K-step — vmcnt drain overlaps with compute). LDS = 2 x 32KB.
__device__ __forceinline__ void gemm_loop_f16(
        const ushort* __restrict__ Ag, int ap,
        const ushort* __restrict__ Bg, int bp,
        int K, ushort* lds, f32x4 acc[4][4]) {
    const int t = threadIdx.x;
    const int lane = t & 63, w = t >> 6;
    const int lr = lane & 15, kg = lane >> 4;
    const int wm = (w >> 1) << 6, wn = (w & 1) << 6;
    const int rowl = lane >> 3;
    const int cs = (lane & 7) ^ rowl;    // swizzled source chunk (both-sides rule)
    const ushort* sA = Ag + cs * 8;
    const ushort* sB = Bg + cs * 8;
    const int rb = (w << 3) + rowl;
    const int ldsb = w << 9;
    const int cA0 = kg ^ (lr & 7);
    const int cA1 = (kg | 4) ^ (lr & 7);
    const int nt = K >> 6;
    // prologue: stage tile 0 into buf 0
    #pragma unroll
    for (int q = 0; q < 4; ++q) {
        int r = rb + (q << 5);
        gl_lds16(sA + (size_t)r * ap, lds + ldsb + (q << 11));
        gl_lds16(sB + (size_t)r * bp, lds + 8192 + ldsb + (q << 11));
    }
    __syncthreads();
    int buf = 0;
    for (int tile = 0; tile < nt; ++tile) {
        // issue next tile's async loads into the other buffer
        if (tile + 1 < nt) {
            int nb = (buf ^ 1) << 14;
            int k0 = (tile + 1) << 6;
            #pragma unroll
            for (int q = 0; q < 4; ++q) {
                int r = rb + (q << 5);
                gl_lds16(sA + (size_t)r * ap + k0, lds + nb + ldsb + (q << 11));
                gl_lds16(sB + (size_t)r * bp + k0, lds + nb + 8192 + ldsb + (q << 11));
            }
        }
        // compute current buffer
        const ushort* Ab = lds + (buf << 14);
        const ushort* Bb = Ab + 8192;
        #pragma unroll
        for (int s = 0; s < 2; ++s) {
            int ch = s ? cA1 : cA0;
            f16x8 a[4], b[4];
            #pragma unroll
            for (int i = 0; i < 4; ++i) {
                a[i] = *(const f16x8*)&Ab[((wm + i * 16 + lr) << 6) + ch * 8];
                b[i] = *(const f16x8*)&Bb[((wn + i * 16 + lr) << 6) + ch * 8];
            }
            #pragma unroll
            for (int i = 0; i < 4; ++i)
                #pragma unroll
                for (int j = 0; j < 4; ++j)
                    acc[i][j] = __builtin_amdgcn_mfma_f32_16x16x32_f16(a[i], b[j], acc[i][j], 0, 0, 0);
        }
        __syncthreads();   // drains vmcnt (next buf ready) after compute covered latency
        buf ^= 1;
    }
}

__global__ __launch_bounds__(256) void qkv_f16(
        const ushort* __restrict__ Wh, const ushort* __restrict__ xh,
        const float* __restrict__ qb, const float* __restrict__ kb,
        const float* __restrict__ vb,
        ushort* __restrict__ qt, ushort* __restrict__ kt, ushort* __restrict__ v) {
    __shared__ __align__(16) ushort lds[32768];   // 64 KB: 2-phase staging / epilogue reuse
    int n = blockIdx.z, m0 = blockIdx.y << 7, j0 = blockIdx.x << 7;
    f32x4 acc[4][4];
    #pragma unroll
    for (int i = 0; i < 4; ++i)
        #pragma unroll
        for (int j = 0; j < 4; ++j) acc[i][j] = (f32x4){0.f, 0.f, 0.f, 0.f};
    gemm_loop_f16(Wh + (size_t)m0 * CC, CC,
                  xh + ((size_t)(n * HW + j0)) * CC, CC, CC, lds, acc);
    const int t = threadIdx.x, lane = t & 63, wid = t >> 6;
    const int lr = lane & 15, kg = lane >> 4;
    const int wm = (wid >> 1) << 6, wn = (wid & 1) << 6;
    if (m0 < 256) {
        ushort* dst = (m0 == 0) ? qt : kt;
        const float* bp = (m0 == 0) ? qb : kb;
        #pragma unroll
        for (int mi = 0; mi < 4; ++mi)
            #pragma unroll
            for (int nj = 0; nj < 4; ++nj) {
                int m = wm + mi * 16 + kg * 4;
                int j = j0 + wn + nj * 16 + lr;
                ushort4 pk;
                pk.x = f16b(acc[mi][nj][0] + bp[m + 0]);
                pk.y = f16b(acc[mi][nj][1] + bp[m + 1]);
                pk.z = f16b(acc[mi][nj][2] + bp[m + 2]);
                pk.w = f16b(acc[mi][nj][3] + bp[m + 3]);
                *(ushort4*)&dst[((size_t)(n * HW + j) << 7) + m] = pk;
            }
    } else {
        int mo = m0 - 256;
        __syncthreads();   // staging dead; reuse as transpose buffer (128x136)
        #pragma unroll
        for (int mi = 0; mi < 4; ++mi)
            #pragma unroll
            for (int nj = 0; nj < 4; ++nj) {
                int ml = wm + mi * 16 + kg * 4;
                int jl = wn + nj * 16 + lr;
                #pragma unroll
                for (int r = 0; r < 4; ++r)
                    lds[(ml + r) * 136 + jl] = f16b(acc[mi][nj][r] + vb[mo + ml + r]);
            }
        __syncthreads();
        #pragma unroll
        for (int p = 0; p < 8; ++p) {
            int row = (t >> 4) + p * 16;
            int ch = (t & 15) * 8;
            *(uint4*)&v[((size_t)(n * CC + mo + row) << 10) + j0 + ch] =
                *(const uint4*)&lds[row * 136 + ch];
        }
    }
}

__global__ __launch_bounds__(256) void score_f16(
        const ushort* __restrict__ qt, const ushort* __restrict__ kt,
        float* __restrict__ attn) {
    __shared__ __align__(16) ushort lds[32768];
    int n = blockIdx.z, i0 = blockIdx.y << 7, j0 = blockIdx.x << 7;
    f32x4 acc[4][4];
    #pragma unroll
    for (int i = 0; i < 4; ++i)
        #pragma unroll
        for (int j = 0; j < 4; ++j) acc[i][j] = (f32x4){0.f, 0.f, 0.f, 0.f};
    gemm_loop_f16(qt + ((size_t)(n * HW + i0)) * CQK, CQK,
                  kt + ((size_t)(n * HW + j0)) * CQK, CQK, CQK, lds, acc);
    const int t = threadIdx.x, lane = t & 63, wid = t >> 6;
    const int lr = lane & 15, kg = lane >> 4;
    const int wm = (wid >> 1) << 6, wn = (wid & 1) << 6;
    #pragma unroll
    for (int mi = 0; mi < 4; ++mi)
        #pragma unroll
        for (int r = 0; r < 4; ++r) {
            int irow = i0 + wm + mi * 16 + kg * 4 + r;
            #pragma unroll
            for (int nj = 0; nj < 4; ++nj) {
                int j = j0 + wn + nj * 16 + lr;
                attn[((size_t)(n * HW + irow) << 10) + j] = acc[mi][nj][r];
            }
        }
}

// row softmax; float4/ushort4 vectorized; P fp16 written in place
__global__ void softmax_f16(float* __restrict__ attn) {
    int row = blockIdx.x;
    float* p = attn + ((size_t)row << 10);
    int t = threadIdx.x;
    int wid = t >> 6, lane = t & 63;
    float4 v4 = *(const float4*)&p[t << 2];
    float m = fmaxf(fmaxf(v4.x, v4.y), fmaxf(v4.z, v4.w));
    for (int off = 32; off > 0; off >>= 1) m = fmaxf(m, __shfl_xor(m, off));
    __shared__ float redm[4], reds[4];
    if (lane == 0) redm[wid] = m;
    __syncthreads();
    if (t == 0) {
        float mm = fmaxf(fmaxf(redm[0], redm[1]), fmaxf(redm[2], redm[3]));
        redm[0] = mm;
    }
    __syncthreads();
    m = redm[0];
    v4.x = expf(v4.x - m); v4.y = expf(v4.y - m);
    v4.z = expf(v4.z - m); v4.w = expf(v4.w - m);
    float s = v4.x + v4.y + v4.z + v4.w;
    for (int off = 32; off > 0; off >>= 1) s += __shfl_xor(s, off);
    if (lane == 0) reds[wid] = s;
    __syncthreads();
    if (t == 0) reds[0] = reds[0] + reds[1] + reds[2] + reds[3];
    __syncthreads();
    float inv = 1.f / reds[0];
    ushort4 h4;
    h4.x = f16b(v4.x * inv); h4.y = f16b(v4.y * inv);
    h4.z = f16b(v4.z * inv); h4.w = f16b(v4.w * inv);
    *(ushort4*)&((ushort*)p)[t << 2] = h4;
}

__global__ __launch_bounds__(256) void out_f16(
        const ushort* __restrict__ v, const ushort* __restrict__ pus,
        const float* __restrict__ x, const float* __restrict__ gamma,
        float* __restrict__ pmax) {
    __shared__ __align__(16) ushort lds[32768];
    int n = blockIdx.z, c0 = blockIdx.y << 7, i0 = blockIdx.x << 7;
    f32x4 acc[4][4];
    #pragma unroll
    for (int i = 0; i < 4; ++i)
        #pragma unroll
        for (int j = 0; j < 4; ++j) acc[i][j] = (f32x4){0.f, 0.f, 0.f, 0.f};
    gemm_loop_f16(v + ((size_t)(n * CC + c0) << 10), HW,
                  pus + ((size_t)(n * HW + i0)) * 2048, 2048, HW, lds, acc);
    const int t = threadIdx.x, lane = t & 63, wid = t >> 6;
    const int lr = lane & 15, kg = lane >> 4;
    const int wm = (wid >> 1) << 6, wn = (wid & 1) << 6;
    float g = gamma[0];
    __syncthreads();
    float (*smax)[64] = (float(*)[64])lds;
    #pragma unroll
    for (int mi = 0; mi < 4; ++mi)
        #pragma unroll
        for (int r = 0; r < 4; ++r) {
            int c = c0 + wm + mi * 16 + kg * 4 + r;
            const float* xp = x + ((size_t)(n * CC + c) << 10);
            float mx = -INFINITY;
            #pragma unroll
            for (int nj = 0; nj < 4; ++nj) {
                int i = i0 + wn + nj * 16 + lr;
                mx = fmaxf(mx, g * acc[mi][nj][r] + xp[i]);
            }
            #pragma unroll
            for (int off = 1; off < 16; off <<= 1) mx = fmaxf(mx, __shfl_xor(mx, off));
            if (lr == 0) smax[wid][mi * 16 + kg * 4 + r] = mx;
        }
    __syncthreads();
    if (t < 128) {
        int half = t >> 6, cl = t & 63;
        float m = fmaxf(smax[half * 2][cl], smax[half * 2 + 1][cl]);
        pmax[((size_t)(n * 8 + blockIdx.x) << 10) + c0 + half * 64 + cl] = m;
    }
}

__global__ void gf_reduce(const float* __restrict__ pmax, float* __restrict__ gf) {
    int idx = blockIdx.x * 256 + threadIdx.x;
    int n = idx >> 10, c = idx & 1023;
    float m = -INFINITY;
    #pragma unroll
    for (int ib = 0; ib < 8; ++ib)
        m = fmaxf(m, pmax[(((size_t)(n << 3) + ib) << 10) + c]);
    gf[idx] = m;
}

extern "C" void kernel_launch(void* const* d_in, const int* in_sizes, int n_in,
                              void* d_out, int out_size, void* d_ws, size_t ws_size,
                              hipStream_t stream) {
    const float* x      = (const float*)d_in[0];
    const float* head_w = (const float*)d_in[1];
    const float* bn_w   = (const float*)d_in[2];
    const float* bn_b   = (const float*)d_in[3];
    const float* q_w    = (const float*)d_in[4];
    const float* q_b    = (const float*)d_in[5];
    const float* k_w    = (const float*)d_in[6];
    const float* k_b    = (const float*)d_in[7];
    const float* v_w    = (const float*)d_in[8];
    const float* v_b    = (const float*)d_in[9];
    const float* gamma  = (const float*)d_in[10];

    float* out      = (float*)d_out;
    float* out_fg   = out;
    float* out_bg   = out + 16384;
    float* out_ccam = out + 32768;
    float* out_gf   = out + 49152;

    char* B = (char*)d_ws;
    float*  a     = (float*)(B + OFF_A);
    float*  stats = (float*)(B + OFF_STATS);
    float*  cm    = (float*)(B + OFF_CM);
    ushort* Wh    = (ushort*)(B + OFF_WH);
    ushort* qt    = (ushort*)(B + OFF_QT);
    ushort* kt    = (ushort*)(B + OFF_KT);
    ushort* v     = (ushort*)(B + OFF_V);
    ushort* xh    = (ushort*)(B + OFF_XH);
    float*  attn  = (float*)(B + OFF_ATTN);
    float*  pmax  = (float*)(B + OFF_PMAX);
    float*  ypart = (float*)(B + OFF_YP);

    hipLaunchKernelGGL(cvtT_x_conv, dim3(32, 32, 16), dim3(256), 0, stream, x, head_w, xh, ypart);
    hipLaunchKernelGGL(conv_combine, dim3(64), dim3(256), 0, stream, ypart, a);
    hipLaunchKernelGGL(bn_stats, dim3(1), dim3(256), 0, stream, a, stats);
    hipLaunchKernelGGL(ccam_kernel, dim3(64), dim3(256), 0, stream, a, stats, bn_w, bn_b, cm, out_ccam);
    hipLaunchKernelGGL(fgbg_kernel, dim3(4096), dim3(256), 0, stream, x, cm, out_fg, out_bg);

    hipLaunchKernelGGL(cvt_w, dim3(1280), dim3(256), 0, stream, q_w, k_w, v_w, Wh);
    hipLaunchKernelGGL(qkv_f16, dim3(8, 10, 16), dim3(256), 0, stream,
                       Wh, xh, q_b, k_b, v_b, qt, kt, v);
    hipLaunchKernelGGL(score_f16, dim3(8, 8, 16), dim3(256), 0, stream, qt, kt, attn);
    hipLaunchKernelGGL(softmax_f16, dim3(NB * HW), dim3(256), 0, stream, attn);
    hipLaunchKernelGGL(out_f16, dim3(8, 8, 16), dim3(256), 0, stream,
                       v, (const ushort*)attn, x, gamma, pmax);
    hipLaunchKernelGGL(gf_reduce, dim3(64), dim3(256), 0, stream, pmax, out_gf);
}